// Round 4
// baseline (210.092 us; speedup 1.0000x reference)
//
#include <hip/hip_runtime.h>
#include <stdint.h>

typedef __attribute__((ext_vector_type(8)))  short s16x8;   // 8 x bf16
typedef __attribute__((ext_vector_type(16))) float f32x16;  // 32x32 MFMA acc
typedef __attribute__((ext_vector_type(2)))  unsigned u32x2;

union CvtI4 { int4 i; s16x8 s; };
union CvtU4 { uint4 u; s16x8 s; };

__device__ __forceinline__ unsigned f2bf(float f) {
    union { float f; unsigned u; } v; v.f = f;
    return (v.u + 0x7fffu + ((v.u >> 16) & 1u)) >> 16;     // RNE
}

// pack two f32 -> (bf16(lo) | bf16(hi)<<16), round-half-up (v12-verified idiom)
__device__ __forceinline__ unsigned packbf(float lo, float hi) {
    union { float f; unsigned u; } a0, a1;
    a0.f = lo; a1.f = hi;
    return __builtin_amdgcn_perm(a1.u + 0x8000u, a0.u + 0x8000u, 0x07060302u);
}

// ---------------------------------------------------------------------------
// k_prep: grid 1024 = (b, n0-chunk, half). LDS-transpose x tile ->
//   xT[b][n][c] = bf16(x * sqrt(log2e/8)), vbf[b][c][n] = bf16(relu(bn1(w1.x)))
// ---------------------------------------------------------------------------
__global__ __launch_bounds__(256) void k_prep(
    const float* __restrict__ x, const float* __restrict__ w1,
    const float* __restrict__ g1, const float* __restrict__ b1,
    const float* __restrict__ m1, const float* __restrict__ v1,
    unsigned short* __restrict__ xT, unsigned short* __restrict__ vbf)
{
    __shared__ float X[64 * 65];   // [c][n] pad+1
    const int b    = blockIdx.x >> 7;
    const int n0   = ((blockIdx.x >> 1) & 63) << 6;
    const int half = blockIdx.x & 1;
    const int tid  = threadIdx.x;
    const float QS = 0.42466090014400953f;   // sqrt(log2(e)/8)

    {
        const int r = tid >> 6, nn = tid & 63;
        const float* xb = x + (size_t)b * 262144 + n0 + nn;
#pragma unroll
        for (int cc = 0; cc < 16; ++cc) {
            int c = cc * 4 + r;
            X[c * 65 + nn] = xb[(size_t)c * 4096];
        }
    }
    __syncthreads();

    {   // xT: 32 n rows, 8 threads per 128B row
        const int n8 = tid >> 3, c8 = tid & 7;
        const int n = (half << 5) + n8;
        unsigned u[4];
#pragma unroll
        for (int j = 0; j < 4; ++j) {
            unsigned lo = f2bf(X[(c8 * 8 + 2 * j) * 65 + n] * QS);
            unsigned hi = f2bf(X[(c8 * 8 + 2 * j + 1) * 65 + n] * QS);
            u[j] = lo | (hi << 16);
        }
        uint4 pk; pk.x = u[0]; pk.y = u[1]; pk.z = u[2]; pk.w = u[3];
        *(uint4*)(xT + (((size_t)((b << 12) + n0 + n)) << 6) + (c8 << 3)) = pk;
    }

    {   // V = relu(bn1(conv1x1)): 32 output channels for this half
        const int n = tid & 63, og = tid >> 6;
        float rX[64];
#pragma unroll
        for (int c = 0; c < 64; ++c) rX[c] = X[c * 65 + n];
        unsigned short* vb = vbf + (((size_t)(b << 6)) << 12) + n0 + n;
#pragma unroll 2
        for (int oo = 0; oo < 8; ++oo) {
            int o = (half << 5) + og * 8 + oo;
            float inv = g1[o] * rsqrtf(v1[o] + 1e-5f);
            float sh  = b1[o] - m1[o] * inv;
            float acc = 0.f;
#pragma unroll
            for (int c = 0; c < 64; ++c) acc = fmaf(w1[o * 64 + c], rX[c], acc);
            vb[(size_t)o << 12] = (unsigned short)f2bf(fmaxf(fmaf(acc, inv, sh), 0.f));
        }
    }
}

// ---------------------------------------------------------------------------
// k_attn v16: v15 + cross-phase software pipeline (PV deferred one phase).
// Wave w = (qd = w&3, par = w>>2); qd -> (s = m-strip, t = n-half).
// Phase p: [PV(p-1) MFMAs from held regs  -- fills matrix pipe while
//           K-frag ds_reads are in flight] -> QK(p) chain -> exp2+pack ->
//           Gh -> pre-read V frags(p) from Vl[p&1] -> barrier.
// Phase 0 uses zeroed Gh/Bvh (0x0 MFMA, no NaN). Final PV(31) runs
// register-only in the epilogue before LDS scratch reuse.
// All layouts (swizzles, pack, permlane32_swap mapping, stores) are
// byte-identical to the v15-verified ones. One barrier per phase (33).
// LDS 64KB -> 2 blocks/CU. grid 512 = (b=XCD, qgrp).
// ---------------------------------------------------------------------------
__global__ __launch_bounds__(512, 4) void k_attn(
    const unsigned short* __restrict__ xT, const unsigned short* __restrict__ vbf,
    unsigned short* __restrict__ outO)
{
    __shared__ __align__(16) unsigned short Kl[2][2][64 * 64];  // [buf][pt][m][c] swz8
    __shared__ __align__(16) unsigned short Vl[2][2][64 * 64];  // [buf][pt][d][m] swz8

    const int b    = blockIdx.x & 7;          // batch == XCD slice
    const int qgrp = blockIdx.x >> 3;         // 0..63
    const int tid  = threadIdx.x;
    const int w = tid >> 6, lane = tid & 63;
    const int l31 = lane & 31, half = lane >> 5;
    const int qbase = qgrp << 6;
    const int qd = w & 3, par = w >> 2;
    const int s = qd & 1;      // m-strip (QK) / PV k-slice group
    const int t = qd >> 1;     // n-half

    // ---- Q fragments (B operand), rows n = qbase + t*32 + l31 ----
    s16x8 Bq[4];
    {
        const unsigned short* qr = xT +
            (((size_t)((b << 12) + qbase + (t << 5) + l31)) << 6) + (half << 3);
#pragma unroll
        for (int kk = 0; kk < 4; ++kk) {
            CvtI4 c; c.i = *(const int4*)(qr + (kk << 4));
            Bq[kk] = c.s;
        }
    }

    // ---- cooperative staging mapping (512 threads, 2 tiles/phase) ----
    const int pt = tid >> 8;            // tile parity this thread stages
    const int sr = (tid >> 3) & 31;     // rows sr and sr+32
    const int sc = tid & 7;             // 16B chunk
    const unsigned short* kBase = xT  + ((size_t)b << 18) + (sr << 6) + (sc << 3);
    const unsigned short* vBase = vbf + ((size_t)b << 18) + ((size_t)sr << 12) + (sc << 3);
    const int kx  = (sc ^ (sr & 7)) << 3;          // (sr+32)&7 == sr&7
    const int d0  = (sr << 6) + kx;
    const int d1  = ((sr + 32) << 6) + kx;

    int4 kpA, kpB, vpA, vpB;

    // ================= prologue: stage T0 direct, prefetch T1 =================
    {
        int4 a0 = *(const int4*)(kBase + ((size_t)pt << 12));
        int4 a1 = *(const int4*)(kBase + ((size_t)pt << 12) + (32 << 6));
        int4 b0 = *(const int4*)(vBase + (pt << 6));
        int4 b1v = *(const int4*)(vBase + ((size_t)32 << 12) + (pt << 6));
        unsigned short* Kd = &Kl[0][pt][0];
        unsigned short* Vd = &Vl[0][pt][0];
        *(int4*)(Kd + d0) = a0; *(int4*)(Kd + d1) = a1;
        *(int4*)(Vd + d0) = b0; *(int4*)(Vd + d1) = b1v;
        const int t1 = 2 + pt;
        kpA = *(const int4*)(kBase + ((size_t)t1 << 12));
        kpB = *(const int4*)(kBase + ((size_t)t1 << 12) + (32 << 6));
        vpA = *(const int4*)(vBase + (t1 << 6));
        vpB = *(const int4*)(vBase + ((size_t)32 << 12) + (t1 << 6));
    }
    __syncthreads();

    f32x16 O[2];
#pragma unroll
    for (int dl = 0; dl < 2; ++dl)
#pragma unroll
        for (int r = 0; r < 16; ++r) O[dl][r] = 0.f;
    float rs = 0.f;

    // cross-phase pipeline state: packed P and V fragments (zero for phase 0)
    uint2 Gh[4];
    s16x8 Bvh[4];
    {
        const s16x8 z = {0, 0, 0, 0, 0, 0, 0, 0};
#pragma unroll
        for (int q = 0; q < 4; ++q) { Gh[q].x = 0u; Gh[q].y = 0u; }
#pragma unroll
        for (int j = 0; j < 4; ++j) Bvh[j] = z;
    }

    const int km = (s << 5) + l31;

    // ================= main loop: 32 phases, 1 barrier each =================
    for (int p = 0; p < 32; ++p) {
        // stage T(p+1) from regs into buf[(p+1)&1]
        {
            unsigned short* Kd = &Kl[(p + 1) & 1][pt][0];
            unsigned short* Vd = &Vl[(p + 1) & 1][pt][0];
            *(int4*)(Kd + d0) = kpA; *(int4*)(Kd + d1) = kpB;
            *(int4*)(Vd + d0) = vpA; *(int4*)(Vd + d1) = vpB;
        }
        // prefetch T(p+2) (clamped dup at tail, never read)
        {
            int tn = ((p + 2) << 1) + pt; if (tn > 63) tn = 63;
            kpA = *(const int4*)(kBase + ((size_t)tn << 12));
            kpB = *(const int4*)(kBase + ((size_t)tn << 12) + (32 << 6));
            vpA = *(const int4*)(vBase + (tn << 6));
            vpB = *(const int4*)(vBase + ((size_t)32 << 12) + (tn << 6));
        }

        // ---- issue K-frag ds_reads for QK(p) ----
        const unsigned short* Kb = &Kl[p & 1][par][0];
        s16x8 Ak[4];
#pragma unroll
        for (int kk = 0; kk < 4; ++kk)
            Ak[kk] = *(const s16x8*)(Kb + (km << 6) + ((((kk << 1) + half) ^ (km & 7)) << 3));

        // ---- PV(p-1): pure-register MFMAs (cover K ds_read latency) ----
        __builtin_amdgcn_s_setprio(1);
#pragma unroll
        for (int ksl = 0; ksl < 2; ++ksl) {
            u32x2 r0 = __builtin_amdgcn_permlane32_swap(Gh[2*ksl].x, Gh[2*ksl+1].x, false, false);
            u32x2 r1 = __builtin_amdgcn_permlane32_swap(Gh[2*ksl].y, Gh[2*ksl+1].y, false, false);
            CvtU4 ac;
            ac.u.x = r0.x; ac.u.y = r1.x; ac.u.z = r0.y; ac.u.w = r1.y;
            const s16x8 Ap = ac.s;
            O[0] = __builtin_amdgcn_mfma_f32_32x32x16_bf16(Ap, Bvh[2*ksl + 0], O[0], 0, 0, 0);
            O[1] = __builtin_amdgcn_mfma_f32_32x32x16_bf16(Ap, Bvh[2*ksl + 1], O[1], 0, 0, 0);
        }

        // ---- QK quadrant (s,t) of tile 2p+par ----
        f32x16 S = {0.f,0.f,0.f,0.f,0.f,0.f,0.f,0.f,0.f,0.f,0.f,0.f,0.f,0.f,0.f,0.f};
        S = __builtin_amdgcn_mfma_f32_32x32x16_bf16(Ak[0], Bq[0], S, 0, 0, 0);
        S = __builtin_amdgcn_mfma_f32_32x32x16_bf16(Ak[1], Bq[1], S, 0, 0, 0);
        S = __builtin_amdgcn_mfma_f32_32x32x16_bf16(Ak[2], Bq[2], S, 0, 0, 0);
        S = __builtin_amdgcn_mfma_f32_32x32x16_bf16(Ak[3], Bq[3], S, 0, 0, 0);
        __builtin_amdgcn_s_setprio(0);

        // ---- exp2 + pack to bf16 pairs -> Gh (consumed next phase) ----
#pragma unroll
        for (int q = 0; q < 4; ++q) {
            float p0 = __builtin_amdgcn_exp2f(S[4*q+0]);
            float p1 = __builtin_amdgcn_exp2f(S[4*q+1]);
            float p2 = __builtin_amdgcn_exp2f(S[4*q+2]);
            float p3 = __builtin_amdgcn_exp2f(S[4*q+3]);
            rs += (p0 + p1) + (p2 + p3);
            Gh[q].x = packbf(p0, p1);
            Gh[q].y = packbf(p2, p3);
        }

        // ---- pre-read V frags(p) (Vl[p&1] valid until end-of-phase barrier) ----
        {
            const unsigned short* Vb = &Vl[p & 1][par][0];
#pragma unroll
            for (int ksl = 0; ksl < 2; ++ksl)
#pragma unroll
                for (int dl = 0; dl < 2; ++dl) {
                    const int drow = (dl << 5) + l31;
                    const int cch = (s << 2) + (ksl << 1) + half;
                    Bvh[2*ksl + dl] =
                        *(const s16x8*)(Vb + (drow << 6) + ((cch ^ (drow & 7)) << 3));
                }
        }

        __syncthreads();
    }

    // ---- final PV(31): register-only, safe after barrier ----
#pragma unroll
    for (int ksl = 0; ksl < 2; ++ksl) {
        u32x2 r0 = __builtin_amdgcn_permlane32_swap(Gh[2*ksl].x, Gh[2*ksl+1].x, false, false);
        u32x2 r1 = __builtin_amdgcn_permlane32_swap(Gh[2*ksl].y, Gh[2*ksl+1].y, false, false);
        CvtU4 ac;
        ac.u.x = r0.x; ac.u.y = r1.x; ac.u.z = r0.y; ac.u.w = r1.y;
        const s16x8 Ap = ac.s;
        O[0] = __builtin_amdgcn_mfma_f32_32x32x16_bf16(Ap, Bvh[2*ksl + 0], O[0], 0, 0, 0);
        O[1] = __builtin_amdgcn_mfma_f32_32x32x16_bf16(Ap, Bvh[2*ksl + 1], O[1], 0, 0, 0);
    }

    // ================= epilogue: tree-sum O over (s,par); denom; store =====
    float* scr  = (float*)&Kl[0][0][0];        // 8192 f32 (par-merge scratch)
    float* scr2 = (float*)&Vl[0][0][0];        // 4096 f32 (s-merge scratch)
    float* rsL  = scr2 + 4096;                 // 256 f32: [w][l31]
    float* dnm  = rsL + 256;                   // 64 f32

    rs += __shfl_xor(rs, 32);
    if (half == 0) rsL[(w << 5) + l31] = rs;
    if (par == 1) {
#pragma unroll
        for (int dl = 0; dl < 2; ++dl)
#pragma unroll
            for (int r = 0; r < 16; ++r)
                scr[((((qd << 1) + dl)) << 10) + (r << 6) + lane] = O[dl][r];
    }
    __syncthreads();

    if (tid < 64) {
        int tt = tid >> 5, n = tid & 31;
        dnm[tid] = (rsL[((tt << 1) << 5) + n] + rsL[(((tt << 1) + 1) << 5) + n]) +
                   (rsL[(((tt << 1) + 4) << 5) + n] + rsL[(((tt << 1) + 5) << 5) + n]);
    }
    if (par == 0) {
#pragma unroll
        for (int dl = 0; dl < 2; ++dl)
#pragma unroll
            for (int r = 0; r < 16; ++r)
                O[dl][r] += scr[((((qd << 1) + dl)) << 10) + (r << 6) + lane];
        if (s == 1) {
#pragma unroll
            for (int dl = 0; dl < 2; ++dl)
#pragma unroll
                for (int r = 0; r < 16; ++r)
                    scr2[((((t << 1) + dl)) << 10) + (r << 6) + lane] = O[dl][r];
        }
    }
    __syncthreads();

    if (par == 0 && s == 0) {
        const int nb = (b << 12) + qbase;
#pragma unroll
        for (int r = 0; r < 16; ++r) {
            int rowoff = (r & 3) + ((r >> 2) << 3) + (half << 2);
            int n = (t << 5) + rowoff;
            float inv = 1.f / dnm[n];
#pragma unroll
            for (int dl = 0; dl < 2; ++dl) {
                float o = O[dl][r] + scr2[((((t << 1) + dl)) << 10) + (r << 6) + lane];
                outO[((size_t)(nb + n) << 6) + (dl << 5) + l31] =
                    (unsigned short)f2bf(o * inv);
            }
        }
    }
}

// ---------------------------------------------------------------------------
// k_post: stage 3-row attn window (bf16, already normalized) into LDS ->
// dwconv3x3 + BN2 + ReLU -> LDS -> pointwise(w3) + BN3 + residual.
// grid 512 = (b, h), 256 thr.
// ---------------------------------------------------------------------------
__global__ __launch_bounds__(256) void k_post(
    const unsigned short* __restrict__ Obase,
    const float* __restrict__ x,
    const float* __restrict__ w2,
    const float* __restrict__ g2, const float* __restrict__ b2,
    const float* __restrict__ m2, const float* __restrict__ v2,
    const float* __restrict__ w3,
    const float* __restrict__ g3, const float* __restrict__ b3,
    const float* __restrict__ m3, const float* __restrict__ v3,
    float* __restrict__ out)
{
    __shared__ float W[3][64 * 66];
    __shared__ float T2[64 * 66];

    const int b = blockIdx.x >> 6;
    const int h = blockIdx.x & 63;
    const int tid = threadIdx.x;

#pragma unroll
    for (int r = 0; r < 3; ++r) {
        int hh = h + r - 1;
        if (hh >= 0 && hh <= 63) {
#pragma unroll
            for (int i = 0; i < 2; ++i) {
                int lin = (i << 8) + tid;            // 512 = 64 w x 8 chunks
                int w = lin >> 3, cg = lin & 7;
                size_t npos = (size_t)((b << 12) + (hh << 6) + w);
                uint4 v = *(const uint4*)(Obase + (npos << 6) + (cg << 3));
                float* Wd = &W[r][w * 66 + (cg << 3)];
                union { float f; unsigned u; } t;
                t.u = v.x << 16;         Wd[0] = t.f;
                t.u = v.x & 0xFFFF0000u; Wd[1] = t.f;
                t.u = v.y << 16;         Wd[2] = t.f;
                t.u = v.y & 0xFFFF0000u; Wd[3] = t.f;
                t.u = v.z << 16;         Wd[4] = t.f;
                t.u = v.z & 0xFFFF0000u; Wd[5] = t.f;
                t.u = v.w << 16;         Wd[6] = t.f;
                t.u = v.w & 0xFFFF0000u; Wd[7] = t.f;
            }
        } else {
#pragma unroll
            for (int i = 0; i < 2; ++i) {
                int lin = (i << 8) + tid;
                float* Wd = &W[r][(lin >> 3) * 66 + ((lin & 7) << 3)];
#pragma unroll
                for (int j = 0; j < 8; ++j) Wd[j] = 0.f;
            }
        }
    }
    __syncthreads();

    const int w = tid & 63, cq = tid >> 6;
    float t16[16];
#pragma unroll
    for (int i = 0; i < 16; ++i) t16[i] = 0.f;

#pragma unroll
    for (int ky = 0; ky < 3; ++ky) {
#pragma unroll
        for (int kx = 0; kx < 3; ++kx) {
            int ww = w + kx - 1;
            if (ww < 0 || ww > 63) continue;
            const int k = ky * 3 + kx;
            const float* Wr = &W[ky][ww * 66 + (cq << 4)];
#pragma unroll
            for (int i = 0; i < 4; ++i) {
                float4 a = *(const float4*)(Wr + (i << 2));
                int c = (cq << 4) + (i << 2);
                t16[i * 4 + 0] = fmaf(w2[(c + 0) * 9 + k], a.x, t16[i * 4 + 0]);
                t16[i * 4 + 1] = fmaf(w2[(c + 1) * 9 + k], a.y, t16[i * 4 + 1]);
                t16[i * 4 + 2] = fmaf(w2[(c + 2) * 9 + k], a.z, t16[i * 4 + 2]);
                t16[i * 4 + 3] = fmaf(w2[(c + 3) * 9 + k], a.w, t16[i * 4 + 3]);
            }
        }
    }
#pragma unroll
    for (int i = 0; i < 16; ++i) {
        int c = (cq << 4) + i;
        float inv = g2[c] * rsqrtf(v2[c] + 1e-5f);
        float sh  = b2[c] - m2[c] * inv;
        T2[w * 66 + c] = fmaxf(fmaf(t16[i], inv, sh), 0.f);
    }
    __syncthreads();

    float rT[64];
#pragma unroll
    for (int c4 = 0; c4 < 16; ++c4)
        *(float4*)&rT[c4 << 2] = *(const float4*)&T2[w * 66 + (c4 << 2)];

    const int hw = (h << 6) + w;
#pragma unroll 2
    for (int oo = 0; oo < 16; ++oo) {
        int o = (cq << 4) + oo;
        float inv = g3[o] * rsqrtf(v3[o] + 1e-5f);
        float sh  = b3[o] - m3[o] * inv;
        float acc = 0.f;
#pragma unroll
        for (int c = 0; c < 64; ++c) acc = fmaf(w3[o * 64 + c], rT[c], acc);
        size_t idx = (((size_t)((b << 6) + o)) << 12) + hw;
        out[idx] = fmaf(acc, inv, sh) + x[idx];
    }
}

// ---------------------------------------------------------------------------
extern "C" void kernel_launch(void* const* d_in, const int* in_sizes, int n_in,
                              void* d_out, int out_size, void* d_ws, size_t ws_size,
                              hipStream_t stream)
{
    const float* x  = (const float*)d_in[0];
    const float* w1 = (const float*)d_in[1];
    const float* g1 = (const float*)d_in[2];
    const float* b1 = (const float*)d_in[3];
    const float* m1 = (const float*)d_in[4];
    const float* v1 = (const float*)d_in[5];
    const float* w2 = (const float*)d_in[6];
    const float* g2 = (const float*)d_in[7];
    const float* b2 = (const float*)d_in[8];
    const float* m2 = (const float*)d_in[9];
    const float* v2 = (const float*)d_in[10];
    const float* w3 = (const float*)d_in[11];
    const float* g3 = (const float*)d_in[12];
    const float* b3 = (const float*)d_in[13];
    const float* m3 = (const float*)d_in[14];
    const float* v3 = (const float*)d_in[15];
    float* out = (float*)d_out;

    // ws: xT 4MB | vbf 4MB | O 4MB (bf16, normalized)
    unsigned short* xT  = (unsigned short*)d_ws;
    unsigned short* vbf = xT + (size_t)8 * 4096 * 64;
    unsigned short* Obase = (unsigned short*)((char*)d_ws + (8u << 20));

    k_prep<<<1024, 256, 0, stream>>>(x, w1, g1, b1, m1, v1, xT, vbf);
    k_attn<<<512, 512, 0, stream>>>(xT, vbf, Obase);
    k_post<<<512, 256, 0, stream>>>(Obase, x, w2, g2, b2, m2, v2,
                                    w3, g3, b3, m3, v3, out);
}

// Round 5
// 184.795 us; speedup vs baseline: 1.1369x; 1.1369x over previous
//
#include <hip/hip_runtime.h>
#include <stdint.h>

typedef __attribute__((ext_vector_type(8)))  short s16x8;   // 8 x bf16
typedef __attribute__((ext_vector_type(16))) float f32x16;  // 32x32 MFMA acc
typedef __attribute__((ext_vector_type(2)))  unsigned u32x2;

union CvtI4 { int4 i; s16x8 s; };
union CvtU4 { uint4 u; s16x8 s; };

__device__ __forceinline__ unsigned f2bf(float f) {
    union { float f; unsigned u; } v; v.f = f;
    return (v.u + 0x7fffu + ((v.u >> 16) & 1u)) >> 16;     // RNE
}

// pack two f32 -> (bf16(lo) | bf16(hi)<<16), round-half-up (v12-verified idiom)
__device__ __forceinline__ unsigned packbf(float lo, float hi) {
    union { float f; unsigned u; } a0, a1;
    a0.f = lo; a1.f = hi;
    return __builtin_amdgcn_perm(a1.u + 0x8000u, a0.u + 0x8000u, 0x07060302u);
}

// ---------------------------------------------------------------------------
// k_prep: grid 1024 = (b, n0-chunk, half). LDS-transpose x tile ->
//   xT[b][n][c] = bf16(x * sqrt(log2e/8)), vbf[b][c][n] = bf16(relu(bn1(w1.x)))
// ---------------------------------------------------------------------------
__global__ __launch_bounds__(256) void k_prep(
    const float* __restrict__ x, const float* __restrict__ w1,
    const float* __restrict__ g1, const float* __restrict__ b1,
    const float* __restrict__ m1, const float* __restrict__ v1,
    unsigned short* __restrict__ xT, unsigned short* __restrict__ vbf)
{
    __shared__ float X[64 * 65];   // [c][n] pad+1
    const int b    = blockIdx.x >> 7;
    const int n0   = ((blockIdx.x >> 1) & 63) << 6;
    const int half = blockIdx.x & 1;
    const int tid  = threadIdx.x;
    const float QS = 0.42466090014400953f;   // sqrt(log2(e)/8)

    {
        const int r = tid >> 6, nn = tid & 63;
        const float* xb = x + (size_t)b * 262144 + n0 + nn;
#pragma unroll
        for (int cc = 0; cc < 16; ++cc) {
            int c = cc * 4 + r;
            X[c * 65 + nn] = xb[(size_t)c * 4096];
        }
    }
    __syncthreads();

    {   // xT: 32 n rows, 8 threads per 128B row
        const int n8 = tid >> 3, c8 = tid & 7;
        const int n = (half << 5) + n8;
        unsigned u[4];
#pragma unroll
        for (int j = 0; j < 4; ++j) {
            unsigned lo = f2bf(X[(c8 * 8 + 2 * j) * 65 + n] * QS);
            unsigned hi = f2bf(X[(c8 * 8 + 2 * j + 1) * 65 + n] * QS);
            u[j] = lo | (hi << 16);
        }
        uint4 pk; pk.x = u[0]; pk.y = u[1]; pk.z = u[2]; pk.w = u[3];
        *(uint4*)(xT + (((size_t)((b << 12) + n0 + n)) << 6) + (c8 << 3)) = pk;
    }

    {   // V = relu(bn1(conv1x1)): 32 output channels for this half
        const int n = tid & 63, og = tid >> 6;
        float rX[64];
#pragma unroll
        for (int c = 0; c < 64; ++c) rX[c] = X[c * 65 + n];
        unsigned short* vb = vbf + (((size_t)(b << 6)) << 12) + n0 + n;
#pragma unroll 2
        for (int oo = 0; oo < 8; ++oo) {
            int o = (half << 5) + og * 8 + oo;
            float inv = g1[o] * rsqrtf(v1[o] + 1e-5f);
            float sh  = b1[o] - m1[o] * inv;
            float acc = 0.f;
#pragma unroll
            for (int c = 0; c < 64; ++c) acc = fmaf(w1[o * 64 + c], rX[c], acc);
            vb[(size_t)o << 12] = (unsigned short)f2bf(fmaxf(fmaf(acc, inv, sh), 0.f));
        }
    }
}

// ---------------------------------------------------------------------------
// k_attn v15 (verified 53.7us): 8 balanced waves, in-register P.
// Wave w = (qd = w&3, par = w>>2); qd -> (s = m-strip, t = n-half).
// Phase p handles tiles {2p, 2p+1}; wave works on tile 2p+par.
// QK: A = K rows (LDS, swz8), B = Q rows (regs). D col = n = lane&31,
// reg r -> m-offset (r&3)+8*(r>>2)+4*half  => P is lane-local in n.
// exp2 -> packbf pairs G[q] -> permlane32_swap builds the PV A-fragment:
//   (dw0,dw2) = swap(G[2ksl].x, G[2ksl+1].x), (dw1,dw3) = swap(.y,.y).
// Epilogue tree-sums partial O over (s,par). One barrier per phase (33).
// LDS 64KB -> 2 blocks/CU. grid 512 = (b=XCD, qgrp).
// NOTE (R4 lesson): do NOT hold P/V fragments across the barrier — the
// extra 24 VGPRs spill at launch_bounds(512,4) (R4: WRITE_SIZE 4->17MB).
// ---------------------------------------------------------------------------
__global__ __launch_bounds__(512, 4) void k_attn(
    const unsigned short* __restrict__ xT, const unsigned short* __restrict__ vbf,
    unsigned short* __restrict__ outO)
{
    __shared__ __align__(16) unsigned short Kl[2][2][64 * 64];  // [buf][pt][m][c] swz8
    __shared__ __align__(16) unsigned short Vl[2][2][64 * 64];  // [buf][pt][d][m] swz8

    const int b    = blockIdx.x & 7;          // batch == XCD slice
    const int qgrp = blockIdx.x >> 3;         // 0..63
    const int tid  = threadIdx.x;
    const int w = tid >> 6, lane = tid & 63;
    const int l31 = lane & 31, half = lane >> 5;
    const int qbase = qgrp << 6;
    const int qd = w & 3, par = w >> 2;
    const int s = qd & 1;      // m-strip (QK) / PV k-slice group
    const int t = qd >> 1;     // n-half

    // ---- Q fragments (B operand), rows n = qbase + t*32 + l31 ----
    s16x8 Bq[4];
    {
        const unsigned short* qr = xT +
            (((size_t)((b << 12) + qbase + (t << 5) + l31)) << 6) + (half << 3);
#pragma unroll
        for (int kk = 0; kk < 4; ++kk) {
            CvtI4 c; c.i = *(const int4*)(qr + (kk << 4));
            Bq[kk] = c.s;
        }
    }

    // ---- cooperative staging mapping (512 threads, 2 tiles/phase) ----
    const int pt = tid >> 8;            // tile parity this thread stages
    const int sr = (tid >> 3) & 31;     // rows sr and sr+32
    const int sc = tid & 7;             // 16B chunk
    const unsigned short* kBase = xT  + ((size_t)b << 18) + (sr << 6) + (sc << 3);
    const unsigned short* vBase = vbf + ((size_t)b << 18) + ((size_t)sr << 12) + (sc << 3);
    const int kx  = (sc ^ (sr & 7)) << 3;          // (sr+32)&7 == sr&7
    const int d0  = (sr << 6) + kx;
    const int d1  = ((sr + 32) << 6) + kx;

    int4 kpA, kpB, vpA, vpB;

    // ================= prologue: stage T0 direct, prefetch T1 =================
    {
        int4 a0 = *(const int4*)(kBase + ((size_t)pt << 12));
        int4 a1 = *(const int4*)(kBase + ((size_t)pt << 12) + (32 << 6));
        int4 b0 = *(const int4*)(vBase + (pt << 6));
        int4 b1v = *(const int4*)(vBase + ((size_t)32 << 12) + (pt << 6));
        unsigned short* Kd = &Kl[0][pt][0];
        unsigned short* Vd = &Vl[0][pt][0];
        *(int4*)(Kd + d0) = a0; *(int4*)(Kd + d1) = a1;
        *(int4*)(Vd + d0) = b0; *(int4*)(Vd + d1) = b1v;
        const int t1 = 2 + pt;
        kpA = *(const int4*)(kBase + ((size_t)t1 << 12));
        kpB = *(const int4*)(kBase + ((size_t)t1 << 12) + (32 << 6));
        vpA = *(const int4*)(vBase + (t1 << 6));
        vpB = *(const int4*)(vBase + ((size_t)32 << 12) + (t1 << 6));
    }
    __syncthreads();

    f32x16 O[2];
#pragma unroll
    for (int dl = 0; dl < 2; ++dl)
#pragma unroll
        for (int r = 0; r < 16; ++r) O[dl][r] = 0.f;
    float rs = 0.f;

    const int km = (s << 5) + l31;

    // ================= main loop: 32 phases, 1 barrier each =================
    for (int p = 0; p < 32; ++p) {
        // stage T(p+1) from regs into buf[(p+1)&1]
        {
            unsigned short* Kd = &Kl[(p + 1) & 1][pt][0];
            unsigned short* Vd = &Vl[(p + 1) & 1][pt][0];
            *(int4*)(Kd + d0) = kpA; *(int4*)(Kd + d1) = kpB;
            *(int4*)(Vd + d0) = vpA; *(int4*)(Vd + d1) = vpB;
        }
        // prefetch T(p+2) (clamped dup at tail, never read)
        {
            int tn = ((p + 2) << 1) + pt; if (tn > 63) tn = 63;
            kpA = *(const int4*)(kBase + ((size_t)tn << 12));
            kpB = *(const int4*)(kBase + ((size_t)tn << 12) + (32 << 6));
            vpA = *(const int4*)(vBase + (tn << 6));
            vpB = *(const int4*)(vBase + ((size_t)32 << 12) + (tn << 6));
        }

        // ---- QK quadrant (s,t) of tile 2p+par ----
        const unsigned short* Kb = &Kl[p & 1][par][0];
        s16x8 Ak[4];
#pragma unroll
        for (int kk = 0; kk < 4; ++kk)
            Ak[kk] = *(const s16x8*)(Kb + (km << 6) + ((((kk << 1) + half) ^ (km & 7)) << 3));
        f32x16 S = {0.f,0.f,0.f,0.f,0.f,0.f,0.f,0.f,0.f,0.f,0.f,0.f,0.f,0.f,0.f,0.f};
        __builtin_amdgcn_s_setprio(1);
        S = __builtin_amdgcn_mfma_f32_32x32x16_bf16(Ak[0], Bq[0], S, 0, 0, 0);
        S = __builtin_amdgcn_mfma_f32_32x32x16_bf16(Ak[1], Bq[1], S, 0, 0, 0);
        S = __builtin_amdgcn_mfma_f32_32x32x16_bf16(Ak[2], Bq[2], S, 0, 0, 0);
        S = __builtin_amdgcn_mfma_f32_32x32x16_bf16(Ak[3], Bq[3], S, 0, 0, 0);
        __builtin_amdgcn_s_setprio(0);

        // ---- exp2 + pack to bf16 pairs (m-group q, lane-local in n) ----
        uint2 G[4];
#pragma unroll
        for (int q = 0; q < 4; ++q) {
            float p0 = __builtin_amdgcn_exp2f(S[4*q+0]);
            float p1 = __builtin_amdgcn_exp2f(S[4*q+1]);
            float p2 = __builtin_amdgcn_exp2f(S[4*q+2]);
            float p3 = __builtin_amdgcn_exp2f(S[4*q+3]);
            rs += (p0 + p1) + (p2 + p3);
            G[q].x = packbf(p0, p1);
            G[q].y = packbf(p2, p3);
        }

        // ---- PV: in-register P via permlane32_swap; B = V rows from LDS ----
        const unsigned short* Vb = &Vl[p & 1][par][0];
        __builtin_amdgcn_s_setprio(1);
#pragma unroll
        for (int ksl = 0; ksl < 2; ++ksl) {
            // swap(a,b) -> r.x = a.lo||b.lo (dw-low), r.y = a.hi||b.hi (dw-high)
            u32x2 r0 = __builtin_amdgcn_permlane32_swap(G[2*ksl].x, G[2*ksl+1].x, false, false);
            u32x2 r1 = __builtin_amdgcn_permlane32_swap(G[2*ksl].y, G[2*ksl+1].y, false, false);
            CvtU4 ac;
            ac.u.x = r0.x;   // elems 0,1  (src half 0)
            ac.u.y = r1.x;   // elems 2,3  (src half 0)
            ac.u.z = r0.y;   // elems 4,5  (src half 1)
            ac.u.w = r1.y;   // elems 6,7  (src half 1)
            const s16x8 Ap = ac.s;
#pragma unroll
            for (int dl = 0; dl < 2; ++dl) {
                const int drow = (dl << 5) + l31;
                const int cch = (s << 2) + (ksl << 1) + half;   // global 16B chunk in m
                const s16x8 Bv = *(const s16x8*)(Vb + (drow << 6) + ((cch ^ (drow & 7)) << 3));
                O[dl] = __builtin_amdgcn_mfma_f32_32x32x16_bf16(Ap, Bv, O[dl], 0, 0, 0);
            }
        }
        __builtin_amdgcn_s_setprio(0);

        __syncthreads();
    }

    // ================= epilogue: tree-sum O over (s,par); denom; store =====
    float* scr  = (float*)&Kl[0][0][0];        // 8192 f32 (par-merge scratch)
    float* scr2 = (float*)&Vl[0][0][0];        // 4096 f32 (s-merge scratch)
    float* rsL  = scr2 + 4096;                 // 256 f32: [w][l31]
    float* dnm  = rsL + 256;                   // 64 f32

    rs += __shfl_xor(rs, 32);
    if (half == 0) rsL[(w << 5) + l31] = rs;
    if (par == 1) {
#pragma unroll
        for (int dl = 0; dl < 2; ++dl)
#pragma unroll
            for (int r = 0; r < 16; ++r)
                scr[((((qd << 1) + dl)) << 10) + (r << 6) + lane] = O[dl][r];
    }
    __syncthreads();

    if (tid < 64) {
        int tt = tid >> 5, n = tid & 31;
        dnm[tid] = (rsL[((tt << 1) << 5) + n] + rsL[(((tt << 1) + 1) << 5) + n]) +
                   (rsL[(((tt << 1) + 4) << 5) + n] + rsL[(((tt << 1) + 5) << 5) + n]);
    }
    if (par == 0) {
#pragma unroll
        for (int dl = 0; dl < 2; ++dl)
#pragma unroll
            for (int r = 0; r < 16; ++r)
                O[dl][r] += scr[((((qd << 1) + dl)) << 10) + (r << 6) + lane];
        if (s == 1) {
#pragma unroll
            for (int dl = 0; dl < 2; ++dl)
#pragma unroll
                for (int r = 0; r < 16; ++r)
                    scr2[((((t << 1) + dl)) << 10) + (r << 6) + lane] = O[dl][r];
        }
    }
    __syncthreads();

    if (par == 0 && s == 0) {
        const int nb = (b << 12) + qbase;
#pragma unroll
        for (int r = 0; r < 16; ++r) {
            int rowoff = (r & 3) + ((r >> 2) << 3) + (half << 2);
            int n = (t << 5) + rowoff;
            float inv = 1.f / dnm[n];
#pragma unroll
            for (int dl = 0; dl < 2; ++dl) {
                float o = O[dl][r] + scr2[((((t << 1) + dl)) << 10) + (r << 6) + lane];
                outO[((size_t)(nb + n) << 6) + (dl << 5) + l31] =
                    (unsigned short)f2bf(o * inv);
            }
        }
    }
}

// ---------------------------------------------------------------------------
// k_post v2: split into w-halves for 2x occupancy (R4 theory: k_post was
// latency-bound at 2 blocks/CU, 2 waves/SIMD, with 1024-deep FMA chains).
// grid 1024 = (b, h, wh). Each block: 32 output columns; stages a 3-row x
// 34-col x 64-ch window (zero-padded, so the 3x3 taps are branch-free).
// 256 thr: (w32 = tid&31, cq = tid>>5) -> 8 channels dwconv, 8 outputs
// pointwise. LDS 35.4KB -> 4 blocks/CU, 16 waves/CU.
// ---------------------------------------------------------------------------
__global__ __launch_bounds__(256) void k_post(
    const unsigned short* __restrict__ Obase,
    const float* __restrict__ x,
    const float* __restrict__ w2,
    const float* __restrict__ g2, const float* __restrict__ b2,
    const float* __restrict__ m2, const float* __restrict__ v2,
    const float* __restrict__ w3,
    const float* __restrict__ g3, const float* __restrict__ b3,
    const float* __restrict__ m3, const float* __restrict__ v3,
    float* __restrict__ out)
{
    __shared__ float W[3][34 * 66];   // [row][col][ch] (+2 pad per col)
    __shared__ float T2[32 * 66];

    const int b  = blockIdx.x >> 7;
    const int h  = (blockIdx.x >> 1) & 63;
    const int wh = blockIdx.x & 1;
    const int wbase = wh << 5;
    const int tid = threadIdx.x;

    // stage 3 rows x 34 cols x 64 ch (272 slots of 8ch; 2 passes of 256)
#pragma unroll
    for (int r = 0; r < 3; ++r) {
        int hh = h + r - 1;
#pragma unroll
        for (int i = 0; i < 2; ++i) {
            int lin = (i << 8) + tid;
            if (lin < 272) {
                int wl = lin >> 3, cg = lin & 7;
                int wg = wbase + wl - 1;
                float* Wd = &W[r][wl * 66 + (cg << 3)];
                if (hh >= 0 && hh <= 63 && wg >= 0 && wg <= 63) {
                    size_t npos = (size_t)((b << 12) + (hh << 6) + wg);
                    uint4 v = *(const uint4*)(Obase + (npos << 6) + (cg << 3));
                    union { float f; unsigned u; } t;
                    t.u = v.x << 16;         Wd[0] = t.f;
                    t.u = v.x & 0xFFFF0000u; Wd[1] = t.f;
                    t.u = v.y << 16;         Wd[2] = t.f;
                    t.u = v.y & 0xFFFF0000u; Wd[3] = t.f;
                    t.u = v.z << 16;         Wd[4] = t.f;
                    t.u = v.z & 0xFFFF0000u; Wd[5] = t.f;
                    t.u = v.w << 16;         Wd[6] = t.f;
                    t.u = v.w & 0xFFFF0000u; Wd[7] = t.f;
                } else {
#pragma unroll
                    for (int j = 0; j < 8; ++j) Wd[j] = 0.f;
                }
            }
        }
    }
    __syncthreads();

    const int w32 = tid & 31, cq = tid >> 5;   // cq in [0,8): 8 channels
    float t8[8];
#pragma unroll
    for (int i = 0; i < 8; ++i) t8[i] = 0.f;

#pragma unroll
    for (int ky = 0; ky < 3; ++ky) {
#pragma unroll
        for (int kx = 0; kx < 3; ++kx) {
            const int k = ky * 3 + kx;
            // output col w32 <-> staged col w32+1; tap col = w32+kx (padded)
            const float* Wr = &W[ky][(w32 + kx) * 66 + (cq << 3)];
#pragma unroll
            for (int i = 0; i < 2; ++i) {
                float4 a = *(const float4*)(Wr + (i << 2));
                int c = (cq << 3) + (i << 2);
                t8[i * 4 + 0] = fmaf(w2[(c + 0) * 9 + k], a.x, t8[i * 4 + 0]);
                t8[i * 4 + 1] = fmaf(w2[(c + 1) * 9 + k], a.y, t8[i * 4 + 1]);
                t8[i * 4 + 2] = fmaf(w2[(c + 2) * 9 + k], a.z, t8[i * 4 + 2]);
                t8[i * 4 + 3] = fmaf(w2[(c + 3) * 9 + k], a.w, t8[i * 4 + 3]);
            }
        }
    }
#pragma unroll
    for (int i = 0; i < 8; ++i) {
        int c = (cq << 3) + i;
        float inv = g2[c] * rsqrtf(v2[c] + 1e-5f);
        float sh  = b2[c] - m2[c] * inv;
        T2[w32 * 66 + c] = fmaxf(fmaf(t8[i], inv, sh), 0.f);
    }
    __syncthreads();

    float rT[64];
#pragma unroll
    for (int c4 = 0; c4 < 16; ++c4)
        *(float4*)&rT[c4 << 2] = *(const float4*)&T2[w32 * 66 + (c4 << 2)];

    const int hw = (h << 6) + wbase + w32;
#pragma unroll 2
    for (int oo = 0; oo < 8; ++oo) {
        int o = (cq << 3) + oo;
        float inv = g3[o] * rsqrtf(v3[o] + 1e-5f);
        float sh  = b3[o] - m3[o] * inv;
        float acc = 0.f;
#pragma unroll
        for (int c = 0; c < 64; ++c) acc = fmaf(w3[o * 64 + c], rT[c], acc);
        size_t idx = (((size_t)((b << 6) + o)) << 12) + hw;
        out[idx] = fmaf(acc, inv, sh) + x[idx];
    }
}

// ---------------------------------------------------------------------------
extern "C" void kernel_launch(void* const* d_in, const int* in_sizes, int n_in,
                              void* d_out, int out_size, void* d_ws, size_t ws_size,
                              hipStream_t stream)
{
    const float* x  = (const float*)d_in[0];
    const float* w1 = (const float*)d_in[1];
    const float* g1 = (const float*)d_in[2];
    const float* b1 = (const float*)d_in[3];
    const float* m1 = (const float*)d_in[4];
    const float* v1 = (const float*)d_in[5];
    const float* w2 = (const float*)d_in[6];
    const float* g2 = (const float*)d_in[7];
    const float* b2 = (const float*)d_in[8];
    const float* m2 = (const float*)d_in[9];
    const float* v2 = (const float*)d_in[10];
    const float* w3 = (const float*)d_in[11];
    const float* g3 = (const float*)d_in[12];
    const float* b3 = (const float*)d_in[13];
    const float* m3 = (const float*)d_in[14];
    const float* v3 = (const float*)d_in[15];
    float* out = (float*)d_out;

    // ws: xT 4MB | vbf 4MB | O 4MB (bf16, normalized)
    unsigned short* xT  = (unsigned short*)d_ws;
    unsigned short* vbf = xT + (size_t)8 * 4096 * 64;
    unsigned short* Obase = (unsigned short*)((char*)d_ws + (8u << 20));

    k_prep<<<1024, 256, 0, stream>>>(x, w1, g1, b1, m1, v1, xT, vbf);
    k_attn<<<512, 512, 0, stream>>>(xT, vbf, Obase);
    k_post<<<1024, 256, 0, stream>>>(Obase, x, w2, g2, b2, m2, v2,
                                     w3, g3, b3, m3, v3, out);
}

// Round 7
// 184.659 us; speedup vs baseline: 1.1377x; 1.0007x over previous
//
#include <hip/hip_runtime.h>
#include <stdint.h>

typedef __attribute__((ext_vector_type(8)))  short s16x8;   // 8 x bf16
typedef __attribute__((ext_vector_type(16))) float f32x16;  // 32x32 MFMA acc
typedef __attribute__((ext_vector_type(2)))  unsigned u32x2;

union CvtI4 { int4 i; s16x8 s; };
union CvtU4 { uint4 u; s16x8 s; };

__device__ __forceinline__ unsigned f2bf(float f) {
    union { float f; unsigned u; } v; v.f = f;
    return (v.u + 0x7fffu + ((v.u >> 16) & 1u)) >> 16;     // RNE
}

// pack two f32 -> (bf16(lo) | bf16(hi)<<16), round-half-up (v12-verified idiom)
__device__ __forceinline__ unsigned packbf(float lo, float hi) {
    union { float f; unsigned u; } a0, a1;
    a0.f = lo; a1.f = hi;
    return __builtin_amdgcn_perm(a1.u + 0x8000u, a0.u + 0x8000u, 0x07060302u);
}

// ---------------------------------------------------------------------------
// k_prep: grid 1024 = (b, n0-chunk, half). LDS-transpose x tile ->
//   xT[b][n][c] = bf16(x * sqrt(log2e/8)), vbf[b][c][n] = bf16(relu(bn1(w1.x)))
// ---------------------------------------------------------------------------
__global__ __launch_bounds__(256) void k_prep(
    const float* __restrict__ x, const float* __restrict__ w1,
    const float* __restrict__ g1, const float* __restrict__ b1,
    const float* __restrict__ m1, const float* __restrict__ v1,
    unsigned short* __restrict__ xT, unsigned short* __restrict__ vbf)
{
    __shared__ float X[64 * 65];   // [c][n] pad+1
    const int b    = blockIdx.x >> 7;
    const int n0   = ((blockIdx.x >> 1) & 63) << 6;
    const int half = blockIdx.x & 1;
    const int tid  = threadIdx.x;
    const float QS = 0.42466090014400953f;   // sqrt(log2(e)/8)

    {
        const int r = tid >> 6, nn = tid & 63;
        const float* xb = x + (size_t)b * 262144 + n0 + nn;
#pragma unroll
        for (int cc = 0; cc < 16; ++cc) {
            int c = cc * 4 + r;
            X[c * 65 + nn] = xb[(size_t)c * 4096];
        }
    }
    __syncthreads();

    {   // xT: 32 n rows, 8 threads per 128B row
        const int n8 = tid >> 3, c8 = tid & 7;
        const int n = (half << 5) + n8;
        unsigned u[4];
#pragma unroll
        for (int j = 0; j < 4; ++j) {
            unsigned lo = f2bf(X[(c8 * 8 + 2 * j) * 65 + n] * QS);
            unsigned hi = f2bf(X[(c8 * 8 + 2 * j + 1) * 65 + n] * QS);
            u[j] = lo | (hi << 16);
        }
        uint4 pk; pk.x = u[0]; pk.y = u[1]; pk.z = u[2]; pk.w = u[3];
        *(uint4*)(xT + (((size_t)((b << 12) + n0 + n)) << 6) + (c8 << 3)) = pk;
    }

    {   // V = relu(bn1(conv1x1)): 32 output channels for this half
        const int n = tid & 63, og = tid >> 6;
        float rX[64];
#pragma unroll
        for (int c = 0; c < 64; ++c) rX[c] = X[c * 65 + n];
        unsigned short* vb = vbf + (((size_t)(b << 6)) << 12) + n0 + n;
#pragma unroll 2
        for (int oo = 0; oo < 8; ++oo) {
            int o = (half << 5) + og * 8 + oo;
            float inv = g1[o] * rsqrtf(v1[o] + 1e-5f);
            float sh  = b1[o] - m1[o] * inv;
            float acc = 0.f;
#pragma unroll
            for (int c = 0; c < 64; ++c) acc = fmaf(w1[o * 64 + c], rX[c], acc);
            vb[(size_t)o << 12] = (unsigned short)f2bf(fmaxf(fmaf(acc, inv, sh), 0.f));
        }
    }
}

// ---------------------------------------------------------------------------
// k_attn v17: 128-q blocks (merges the two same-b co-resident v15 blocks).
// R5 analysis: v15 was LDS-throughput-bound (~70% LDS-pipe busy/CU), with
// the 2 blocks/CU staging+reading the SAME K/V stream redundantly.
// grid 256 = (b=XCD, qg2 of 128 q rows), 512 thr, 1 block/CU.
// Wave w = (qd=w&3 -> s,t ; par=w>>2) owns q-slabs t' in {t, t+2}:
//   per phase: 4 Ak reads -> 8 QK MFMA (shared across t'),
//              4 Bv reads -> 8 PV MFMA (shared across t'),  (read:MFMA = 1:2)
//              32 exp2, in-register P via packbf+permlane32_swap (v15 maps).
// Epilogue: par-merge (Kl+Vl as 64KB scratch) -> s-merge (Kl) -> store.
// VGPR ~200 @ launch_bounds(512,2); NO cross-barrier pipeline state (R4).
// ---------------------------------------------------------------------------
__global__ __launch_bounds__(512, 2) void k_attn(
    const unsigned short* __restrict__ xT, const unsigned short* __restrict__ vbf,
    unsigned short* __restrict__ outO)
{
    __shared__ __align__(16) unsigned short Kl[2][2][64 * 64];  // [buf][pt][m][c] swz8
    __shared__ __align__(16) unsigned short Vl[2][2][64 * 64];  // [buf][pt][d][m] swz8
    __shared__ float rsL[8][2][32];
    __shared__ float dnm[128];

    const int b   = blockIdx.x & 7;           // batch == XCD slice
    const int qg2 = blockIdx.x >> 3;          // 0..31 (128-q group)
    const int tid = threadIdx.x;
    const int w = tid >> 6, lane = tid & 63;
    const int l31 = lane & 31, half = lane >> 5;
    const int qbase = qg2 << 7;
    const int qd = w & 3, par = w >> 2;
    const int s = qd & 1;      // m-strip (QK) / PV m-chunk group
    const int t = qd >> 1;     // n-slab low bit; wave owns t' = t, t+2

    // ---- Q fragments (B operand) for both q-slabs ----
    s16x8 Bq[2][4];
#pragma unroll
    for (int ti = 0; ti < 2; ++ti) {
        const unsigned short* qr = xT +
            (((size_t)((b << 12) + qbase + ((t + 2 * ti) << 5) + l31)) << 6) + (half << 3);
#pragma unroll
        for (int kk = 0; kk < 4; ++kk) {
            CvtI4 c; c.i = *(const int4*)(qr + (kk << 4));
            Bq[ti][kk] = c.s;
        }
    }

    // ---- cooperative staging mapping (512 threads, 2 tiles/phase) ----
    const int pt = tid >> 8;            // tile parity this thread stages
    const int sr = (tid >> 3) & 31;     // rows sr and sr+32
    const int sc = tid & 7;             // 16B chunk
    const unsigned short* kBase = xT  + ((size_t)b << 18) + (sr << 6) + (sc << 3);
    const unsigned short* vBase = vbf + ((size_t)b << 18) + ((size_t)sr << 12) + (sc << 3);
    const int kx  = (sc ^ (sr & 7)) << 3;          // (sr+32)&7 == sr&7
    const int d0  = (sr << 6) + kx;
    const int d1  = ((sr + 32) << 6) + kx;

    int4 kpA, kpB, vpA, vpB;

    // ================= prologue: stage T0 direct, prefetch T1 =================
    {
        int4 a0 = *(const int4*)(kBase + ((size_t)pt << 12));
        int4 a1 = *(const int4*)(kBase + ((size_t)pt << 12) + (32 << 6));
        int4 b0 = *(const int4*)(vBase + (pt << 6));
        int4 b1v = *(const int4*)(vBase + ((size_t)32 << 12) + (pt << 6));
        unsigned short* Kd = &Kl[0][pt][0];
        unsigned short* Vd = &Vl[0][pt][0];
        *(int4*)(Kd + d0) = a0; *(int4*)(Kd + d1) = a1;
        *(int4*)(Vd + d0) = b0; *(int4*)(Vd + d1) = b1v;
        const int t1 = 2 + pt;
        kpA = *(const int4*)(kBase + ((size_t)t1 << 12));
        kpB = *(const int4*)(kBase + ((size_t)t1 << 12) + (32 << 6));
        vpA = *(const int4*)(vBase + (t1 << 6));
        vpB = *(const int4*)(vBase + ((size_t)32 << 12) + (t1 << 6));
    }
    __syncthreads();

    f32x16 O[2][2];   // [ti][dl]
#pragma unroll
    for (int ti = 0; ti < 2; ++ti)
#pragma unroll
        for (int dl = 0; dl < 2; ++dl)
#pragma unroll
            for (int r = 0; r < 16; ++r) O[ti][dl][r] = 0.f;
    float rs[2] = {0.f, 0.f};

    const int km = (s << 5) + l31;

    // ================= main loop: 32 phases, 1 barrier each =================
    for (int p = 0; p < 32; ++p) {
        // stage T(p+1) from regs into buf[(p+1)&1]
        {
            unsigned short* Kd = &Kl[(p + 1) & 1][pt][0];
            unsigned short* Vd = &Vl[(p + 1) & 1][pt][0];
            *(int4*)(Kd + d0) = kpA; *(int4*)(Kd + d1) = kpB;
            *(int4*)(Vd + d0) = vpA; *(int4*)(Vd + d1) = vpB;
        }
        // prefetch T(p+2) (clamped dup at tail, never read)
        {
            int tn = ((p + 2) << 1) + pt; if (tn > 63) tn = 63;
            kpA = *(const int4*)(kBase + ((size_t)tn << 12));
            kpB = *(const int4*)(kBase + ((size_t)tn << 12) + (32 << 6));
            vpA = *(const int4*)(vBase + (tn << 6));
            vpB = *(const int4*)(vBase + ((size_t)32 << 12) + (tn << 6));
        }

        // ---- Ak reads (shared across both q-slabs) ----
        const unsigned short* Kb = &Kl[p & 1][par][0];
        s16x8 Ak[4];
#pragma unroll
        for (int kk = 0; kk < 4; ++kk)
            Ak[kk] = *(const s16x8*)(Kb + (km << 6) + ((((kk << 1) + half) ^ (km & 7)) << 3));

        // ---- QK for both q-slabs + exp2/pack ----
        uint2 G[2][4];
#pragma unroll
        for (int ti = 0; ti < 2; ++ti) {
            f32x16 S = {0.f,0.f,0.f,0.f,0.f,0.f,0.f,0.f,0.f,0.f,0.f,0.f,0.f,0.f,0.f,0.f};
            __builtin_amdgcn_s_setprio(1);
            S = __builtin_amdgcn_mfma_f32_32x32x16_bf16(Ak[0], Bq[ti][0], S, 0, 0, 0);
            S = __builtin_amdgcn_mfma_f32_32x32x16_bf16(Ak[1], Bq[ti][1], S, 0, 0, 0);
            S = __builtin_amdgcn_mfma_f32_32x32x16_bf16(Ak[2], Bq[ti][2], S, 0, 0, 0);
            S = __builtin_amdgcn_mfma_f32_32x32x16_bf16(Ak[3], Bq[ti][3], S, 0, 0, 0);
            __builtin_amdgcn_s_setprio(0);
#pragma unroll
            for (int q = 0; q < 4; ++q) {
                float p0 = __builtin_amdgcn_exp2f(S[4*q+0]);
                float p1 = __builtin_amdgcn_exp2f(S[4*q+1]);
                float p2 = __builtin_amdgcn_exp2f(S[4*q+2]);
                float p3 = __builtin_amdgcn_exp2f(S[4*q+3]);
                rs[ti] += (p0 + p1) + (p2 + p3);
                G[ti][q].x = packbf(p0, p1);
                G[ti][q].y = packbf(p2, p3);
            }
        }

        // ---- PV: Bv reads shared across q-slabs; in-register P ----
        const unsigned short* Vb = &Vl[p & 1][par][0];
        __builtin_amdgcn_s_setprio(1);
#pragma unroll
        for (int ksl = 0; ksl < 2; ++ksl) {
            const int cch = (s << 2) + (ksl << 1) + half;   // global 16B chunk in m
            const int dr0 = l31;            // dl=0 rows
            const int dr1 = 32 + l31;       // dl=1 rows
            const s16x8 Bv0 = *(const s16x8*)(Vb + (dr0 << 6) + ((cch ^ (dr0 & 7)) << 3));
            const s16x8 Bv1 = *(const s16x8*)(Vb + (dr1 << 6) + ((cch ^ (dr1 & 7)) << 3));
#pragma unroll
            for (int ti = 0; ti < 2; ++ti) {
                // swap(a,b) -> r.x = a.lo||b.lo (dw-low), r.y = a.hi||b.hi (dw-high)
                u32x2 r0 = __builtin_amdgcn_permlane32_swap(G[ti][2*ksl].x, G[ti][2*ksl+1].x, false, false);
                u32x2 r1 = __builtin_amdgcn_permlane32_swap(G[ti][2*ksl].y, G[ti][2*ksl+1].y, false, false);
                CvtU4 ac;
                ac.u.x = r0.x;   // elems 0,1  (src half 0)
                ac.u.y = r1.x;   // elems 2,3  (src half 0)
                ac.u.z = r0.y;   // elems 4,5  (src half 1)
                ac.u.w = r1.y;   // elems 6,7  (src half 1)
                const s16x8 Ap = ac.s;
                O[ti][0] = __builtin_amdgcn_mfma_f32_32x32x16_bf16(Ap, Bv0, O[ti][0], 0, 0, 0);
                O[ti][1] = __builtin_amdgcn_mfma_f32_32x32x16_bf16(Ap, Bv1, O[ti][1], 0, 0, 0);
            }
        }
        __builtin_amdgcn_s_setprio(0);

        __syncthreads();
    }

    // ================= epilogue: par-merge -> s-merge -> store =============
    float* scrK = (float*)&Kl[0][0][0];   // 8192 f32 (qd 0,1 par-merge; then s-merge)
    float* scrV = (float*)&Vl[0][0][0];   // 8192 f32 (qd 2,3 par-merge)

    rs[0] += __shfl_xor(rs[0], 32);
    rs[1] += __shfl_xor(rs[1], 32);
    if (half == 0) { rsL[w][0][l31] = rs[0]; rsL[w][1][l31] = rs[1]; }

    if (par == 1) {
        float* rg = (qd < 2) ? scrK : scrV;
        const int q1 = qd & 1;
#pragma unroll
        for (int ti = 0; ti < 2; ++ti)
#pragma unroll
            for (int dl = 0; dl < 2; ++dl)
#pragma unroll
                for (int r = 0; r < 16; ++r)
                    rg[(((q1 << 2) + (ti << 1) + dl) << 10) + (r << 6) + lane] = O[ti][dl][r];
    }
    __syncthreads();

    if (tid < 128) {   // denom over 4 waves per n-slab
        int tp = tid >> 5, n32 = tid & 31;
        int ti = tp >> 1, tl = tp & 1;
        dnm[tid] = (rsL[(tl << 1) + 0][ti][n32] + rsL[(tl << 1) + 1][ti][n32]) +
                   (rsL[(tl << 1) + 4][ti][n32] + rsL[(tl << 1) + 5][ti][n32]);
    }
    if (par == 0) {
        float* rg = (qd < 2) ? scrK : scrV;
        const int q1 = qd & 1;
#pragma unroll
        for (int ti = 0; ti < 2; ++ti)
#pragma unroll
            for (int dl = 0; dl < 2; ++dl)
#pragma unroll
                for (int r = 0; r < 16; ++r)
                    O[ti][dl][r] += rg[(((q1 << 2) + (ti << 1) + dl) << 10) + (r << 6) + lane];
    }
    __syncthreads();

    if (par == 0 && s == 1) {
#pragma unroll
        for (int ti = 0; ti < 2; ++ti)
#pragma unroll
            for (int dl = 0; dl < 2; ++dl)
#pragma unroll
                for (int r = 0; r < 16; ++r)
                    scrK[(((t << 2) + (ti << 1) + dl) << 10) + (r << 6) + lane] = O[ti][dl][r];
    }
    __syncthreads();

    if (par == 0 && s == 0) {
        const int nb = (b << 12) + qbase;
#pragma unroll
        for (int ti = 0; ti < 2; ++ti)
#pragma unroll
            for (int dl = 0; dl < 2; ++dl)
#pragma unroll
                for (int r = 0; r < 16; ++r) {
                    int rowoff = (r & 3) + ((r >> 2) << 3) + (half << 2);
                    int n = ((t + 2 * ti) << 5) + rowoff;
                    float o = O[ti][dl][r] +
                              scrK[(((t << 2) + (ti << 1) + dl) << 10) + (r << 6) + lane];
                    outO[((size_t)(nb + n) << 6) + (dl << 5) + l31] =
                        (unsigned short)f2bf(o * (1.f / dnm[n]));
                }
    }
}

// ---------------------------------------------------------------------------
// k_post v2: w-half split. grid 1024 = (b, h, wh), 256 thr.
// ---------------------------------------------------------------------------
__global__ __launch_bounds__(256) void k_post(
    const unsigned short* __restrict__ Obase,
    const float* __restrict__ x,
    const float* __restrict__ w2,
    const float* __restrict__ g2, const float* __restrict__ b2,
    const float* __restrict__ m2, const float* __restrict__ v2,
    const float* __restrict__ w3,
    const float* __restrict__ g3, const float* __restrict__ b3,
    const float* __restrict__ m3, const float* __restrict__ v3,
    float* __restrict__ out)
{
    __shared__ float W[3][34 * 66];   // [row][col][ch] (+2 pad per col)
    __shared__ float T2[32 * 66];

    const int b  = blockIdx.x >> 7;
    const int h  = (blockIdx.x >> 1) & 63;
    const int wh = blockIdx.x & 1;
    const int wbase = wh << 5;
    const int tid = threadIdx.x;

#pragma unroll
    for (int r = 0; r < 3; ++r) {
        int hh = h + r - 1;
#pragma unroll
        for (int i = 0; i < 2; ++i) {
            int lin = (i << 8) + tid;
            if (lin < 272) {
                int wl = lin >> 3, cg = lin & 7;
                int wg = wbase + wl - 1;
                float* Wd = &W[r][wl * 66 + (cg << 3)];
                if (hh >= 0 && hh <= 63 && wg >= 0 && wg <= 63) {
                    size_t npos = (size_t)((b << 12) + (hh << 6) + wg);
                    uint4 v = *(const uint4*)(Obase + (npos << 6) + (cg << 3));
                    union { float f; unsigned u; } t;
                    t.u = v.x << 16;         Wd[0] = t.f;
                    t.u = v.x & 0xFFFF0000u; Wd[1] = t.f;
                    t.u = v.y << 16;         Wd[2] = t.f;
                    t.u = v.y & 0xFFFF0000u; Wd[3] = t.f;
                    t.u = v.z << 16;         Wd[4] = t.f;
                    t.u = v.z & 0xFFFF0000u; Wd[5] = t.f;
                    t.u = v.w << 16;         Wd[6] = t.f;
                    t.u = v.w & 0xFFFF0000u; Wd[7] = t.f;
                } else {
#pragma unroll
                    for (int j = 0; j < 8; ++j) Wd[j] = 0.f;
                }
            }
        }
    }
    __syncthreads();

    const int w32 = tid & 31, cq = tid >> 5;   // cq in [0,8): 8 channels
    float t8[8];
#pragma unroll
    for (int i = 0; i < 8; ++i) t8[i] = 0.f;

#pragma unroll
    for (int ky = 0; ky < 3; ++ky) {
#pragma unroll
        for (int kx = 0; kx < 3; ++kx) {
            const int k = ky * 3 + kx;
            const float* Wr = &W[ky][(w32 + kx) * 66 + (cq << 3)];
#pragma unroll
            for (int i = 0; i < 2; ++i) {
                float4 a = *(const float4*)(Wr + (i << 2));
                int c = (cq << 3) + (i << 2);
                t8[i * 4 + 0] = fmaf(w2[(c + 0) * 9 + k], a.x, t8[i * 4 + 0]);
                t8[i * 4 + 1] = fmaf(w2[(c + 1) * 9 + k], a.y, t8[i * 4 + 1]);
                t8[i * 4 + 2] = fmaf(w2[(c + 2) * 9 + k], a.z, t8[i * 4 + 2]);
                t8[i * 4 + 3] = fmaf(w2[(c + 3) * 9 + k], a.w, t8[i * 4 + 3]);
            }
        }
    }
#pragma unroll
    for (int i = 0; i < 8; ++i) {
        int c = (cq << 3) + i;
        float inv = g2[c] * rsqrtf(v2[c] + 1e-5f);
        float sh  = b2[c] - m2[c] * inv;
        T2[w32 * 66 + c] = fmaxf(fmaf(t8[i], inv, sh), 0.f);
    }
    __syncthreads();

    float rT[64];
#pragma unroll
    for (int c4 = 0; c4 < 16; ++c4)
        *(float4*)&rT[c4 << 2] = *(const float4*)&T2[w32 * 66 + (c4 << 2)];

    const int hw = (h << 6) + wbase + w32;
#pragma unroll 2
    for (int oo = 0; oo < 8; ++oo) {
        int o = (cq << 3) + oo;
        float inv = g3[o] * rsqrtf(v3[o] + 1e-5f);
        float sh  = b3[o] - m3[o] * inv;
        float acc = 0.f;
#pragma unroll
        for (int c = 0; c < 64; ++c) acc = fmaf(w3[o * 64 + c], rT[c], acc);
        size_t idx = (((size_t)((b << 6) + o)) << 12) + hw;
        out[idx] = fmaf(acc, inv, sh) + x[idx];
    }
}

// ---------------------------------------------------------------------------
extern "C" void kernel_launch(void* const* d_in, const int* in_sizes, int n_in,
                              void* d_out, int out_size, void* d_ws, size_t ws_size,
                              hipStream_t stream)
{
    const float* x  = (const float*)d_in[0];
    const float* w1 = (const float*)d_in[1];
    const float* g1 = (const float*)d_in[2];
    const float* b1 = (const float*)d_in[3];
    const float* m1 = (const float*)d_in[4];
    const float* v1 = (const float*)d_in[5];
    const float* w2 = (const float*)d_in[6];
    const float* g2 = (const float*)d_in[7];
    const float* b2 = (const float*)d_in[8];
    const float* m2 = (const float*)d_in[9];
    const float* v2 = (const float*)d_in[10];
    const float* w3 = (const float*)d_in[11];
    const float* g3 = (const float*)d_in[12];
    const float* b3 = (const float*)d_in[13];
    const float* m3 = (const float*)d_in[14];
    const float* v3 = (const float*)d_in[15];
    float* out = (float*)d_out;

    // ws: xT 4MB | vbf 4MB | O 4MB (bf16, normalized)
    unsigned short* xT  = (unsigned short*)d_ws;
    unsigned short* vbf = xT + (size_t)8 * 4096 * 64;
    unsigned short* Obase = (unsigned short*)((char*)d_ws + (8u << 20));

    k_prep<<<1024, 256, 0, stream>>>(x, w1, g1, b1, m1, v1, xT, vbf);
    k_attn<<<256, 512, 0, stream>>>(xT, vbf, Obase);
    k_post<<<1024, 256, 0, stream>>>(Obase, x, w2, g2, b2, m2, v2,
                                     w3, g3, b3, m3, v3, out);
}

// Round 8
// 184.086 us; speedup vs baseline: 1.1413x; 1.0031x over previous
//
#include <hip/hip_runtime.h>
#include <stdint.h>

typedef __attribute__((ext_vector_type(8)))  short s16x8;   // 8 x bf16
typedef __attribute__((ext_vector_type(16))) float f32x16;  // 32x32 MFMA acc
typedef __attribute__((ext_vector_type(2)))  unsigned u32x2;

union CvtI4 { int4 i; s16x8 s; };
union CvtU4 { uint4 u; s16x8 s; };

__device__ __forceinline__ unsigned f2bf(float f) {
    union { float f; unsigned u; } v; v.f = f;
    return (v.u + 0x7fffu + ((v.u >> 16) & 1u)) >> 16;     // RNE
}

// pack two f32 -> (bf16(lo) | bf16(hi)<<16), round-half-up (v12-verified idiom)
__device__ __forceinline__ unsigned packbf(float lo, float hi) {
    union { float f; unsigned u; } a0, a1;
    a0.f = lo; a1.f = hi;
    return __builtin_amdgcn_perm(a1.u + 0x8000u, a0.u + 0x8000u, 0x07060302u);
}

// ---------------------------------------------------------------------------
// k_prep: grid 1024 = (b, n0-chunk, half). LDS-transpose x tile ->
//   xT[b][n][c] = bf16(x * sqrt(log2e/8)), vbf[b][c][n] = bf16(relu(bn1(w1.x)))
// ---------------------------------------------------------------------------
__global__ __launch_bounds__(256) void k_prep(
    const float* __restrict__ x, const float* __restrict__ w1,
    const float* __restrict__ g1, const float* __restrict__ b1,
    const float* __restrict__ m1, const float* __restrict__ v1,
    unsigned short* __restrict__ xT, unsigned short* __restrict__ vbf)
{
    __shared__ float X[64 * 65];   // [c][n] pad+1
    const int b    = blockIdx.x >> 7;
    const int n0   = ((blockIdx.x >> 1) & 63) << 6;
    const int half = blockIdx.x & 1;
    const int tid  = threadIdx.x;
    const float QS = 0.42466090014400953f;   // sqrt(log2(e)/8)

    {
        const int r = tid >> 6, nn = tid & 63;
        const float* xb = x + (size_t)b * 262144 + n0 + nn;
#pragma unroll
        for (int cc = 0; cc < 16; ++cc) {
            int c = cc * 4 + r;
            X[c * 65 + nn] = xb[(size_t)c * 4096];
        }
    }
    __syncthreads();

    {   // xT: 32 n rows, 8 threads per 128B row
        const int n8 = tid >> 3, c8 = tid & 7;
        const int n = (half << 5) + n8;
        unsigned u[4];
#pragma unroll
        for (int j = 0; j < 4; ++j) {
            unsigned lo = f2bf(X[(c8 * 8 + 2 * j) * 65 + n] * QS);
            unsigned hi = f2bf(X[(c8 * 8 + 2 * j + 1) * 65 + n] * QS);
            u[j] = lo | (hi << 16);
        }
        uint4 pk; pk.x = u[0]; pk.y = u[1]; pk.z = u[2]; pk.w = u[3];
        *(uint4*)(xT + (((size_t)((b << 12) + n0 + n)) << 6) + (c8 << 3)) = pk;
    }

    {   // V = relu(bn1(conv1x1)): 32 output channels for this half
        const int n = tid & 63, og = tid >> 6;
        float rX[64];
#pragma unroll
        for (int c = 0; c < 64; ++c) rX[c] = X[c * 65 + n];
        unsigned short* vb = vbf + (((size_t)(b << 6)) << 12) + n0 + n;
#pragma unroll 2
        for (int oo = 0; oo < 8; ++oo) {
            int o = (half << 5) + og * 8 + oo;
            float inv = g1[o] * rsqrtf(v1[o] + 1e-5f);
            float sh  = b1[o] - m1[o] * inv;
            float acc = 0.f;
#pragma unroll
            for (int c = 0; c < 64; ++c) acc = fmaf(w1[o * 64 + c], rX[c], acc);
            vb[(size_t)o << 12] = (unsigned short)f2bf(fmaxf(fmaf(acc, inv, sh), 0.f));
        }
    }
}

// ---------------------------------------------------------------------------
// k_attn v18: 16-wave (1024-thr) block + cross-phase PV in registers.
// R7 lesson: v17 (8 waves, 2/SIMD) had pipes SUMMING to wall (VALU 39 +
// LDS 33 + MFMA 24 ~= 100%): lockstep homogeneous waves at low TLP.
// v18: 4 waves/SIMD (16 waves), per-wave work = v15's verified quadrant
// (qd = s + 2*t2, par): 4 Ak reads, 4 QK MFMA, 16 exp2, 4 Bv reads,
// 4 PV MFMA per phase. Shared single staging stream (v17's traffic).
// Cross-phase ILP: PV(p-1) runs register-only at phase start (hides Ak
// ds_read latency + staging); Bv(p) read into held regs at phase end.
// Holds = Gh(8) + Bvh(16) VGPR; per-wave ~90 < 128 cap @ lb(1024,4)
// (R4's spill was a ~150-reg body at the same cap; falsifier: VGPR=128
// + WRITE_SIZE inflation). All v15-verified maps byte-identical.
// grid 256 = (b=XCD, qg2 of 128 q rows), 1 block/CU.
// ---------------------------------------------------------------------------
__global__ __launch_bounds__(1024, 4) void k_attn(
    const unsigned short* __restrict__ xT, const unsigned short* __restrict__ vbf,
    unsigned short* __restrict__ outO)
{
    __shared__ __align__(16) unsigned short Kl[2][2][64 * 64];  // [buf][pt][m][c] swz8
    __shared__ __align__(16) unsigned short Vl[2][2][64 * 64];  // [buf][pt][d][m] swz8
    __shared__ float rsL[16][32];
    __shared__ float dnm[128];

    const int b   = blockIdx.x & 7;           // batch == XCD slice
    const int qg2 = blockIdx.x >> 3;          // 0..31 (128-q group)
    const int tid = threadIdx.x;
    const int w = tid >> 6, lane = tid & 63;
    const int l31 = lane & 31, half = lane >> 5;
    const int qbase = qg2 << 7;
    const int qd = w & 7, par = w >> 3;
    const int s  = qd & 1;     // m-strip (QK) / PV m-chunk group
    const int t2 = qd >> 1;    // n-slab (0..3), 32 q rows each

    // ---- Q fragments (B operand), rows n = qbase + t2*32 + l31 ----
    s16x8 Bq[4];
    {
        const unsigned short* qr = xT +
            (((size_t)((b << 12) + qbase + (t2 << 5) + l31)) << 6) + (half << 3);
#pragma unroll
        for (int kk = 0; kk < 4; ++kk) {
            CvtI4 c; c.i = *(const int4*)(qr + (kk << 4));
            Bq[kk] = c.s;
        }
    }

    // ---- cooperative staging (1024 thr, 2 tiles/phase, 1 K + 1 V chunk) ----
    const int pt = tid >> 9;            // tile parity this thread stages
    const int u  = tid & 511;
    const int sr = u >> 3;              // row 0..63
    const int sc = u & 7;               // 16B chunk
    const unsigned short* kBase = xT  + ((size_t)b << 18) + (sr << 6) + (sc << 3);
    const unsigned short* vBase = vbf + ((size_t)b << 18) + ((size_t)sr << 12) + (sc << 3);
    const int d = (sr << 6) + ((sc ^ (sr & 7)) << 3);

    int4 kp, vp;

    // ================= prologue: stage T0 direct, prefetch T1 =================
    {
        int4 a0 = *(const int4*)(kBase + ((size_t)pt << 12));
        int4 b0 = *(const int4*)(vBase + (pt << 6));
        *(int4*)(&Kl[0][pt][0] + d) = a0;
        *(int4*)(&Vl[0][pt][0] + d) = b0;
        const int t1 = 2 + pt;
        kp = *(const int4*)(kBase + ((size_t)t1 << 12));
        vp = *(const int4*)(vBase + (t1 << 6));
    }
    __syncthreads();

    f32x16 O[2];
#pragma unroll
    for (int dl = 0; dl < 2; ++dl)
#pragma unroll
        for (int r = 0; r < 16; ++r) O[dl][r] = 0.f;
    float rs = 0.f;

    // cross-phase holds (zero for phase 0: 0x0 MFMA contributes nothing)
    uint2 Gh[4];
    s16x8 Bvh[4];
    {
        const s16x8 z = {0, 0, 0, 0, 0, 0, 0, 0};
#pragma unroll
        for (int q = 0; q < 4; ++q) { Gh[q].x = 0u; Gh[q].y = 0u; }
#pragma unroll
        for (int j = 0; j < 4; ++j) Bvh[j] = z;
    }

    const int km = (s << 5) + l31;

    // ================= main loop: 32 phases, 1 barrier each =================
    for (int p = 0; p < 32; ++p) {
        // stage T(p+1) from regs; prefetch T(p+2) (clamped dup at tail)
        {
            *(int4*)(&Kl[(p + 1) & 1][pt][0] + d) = kp;
            *(int4*)(&Vl[(p + 1) & 1][pt][0] + d) = vp;
            int tn = ((p + 2) << 1) + pt; if (tn > 63) tn = 63;
            kp = *(const int4*)(kBase + ((size_t)tn << 12));
            vp = *(const int4*)(vBase + (tn << 6));
        }

        // ---- issue Ak ds_reads for QK(p) ----
        const unsigned short* Kb = &Kl[p & 1][par][0];
        s16x8 Ak[4];
#pragma unroll
        for (int kk = 0; kk < 4; ++kk)
            Ak[kk] = *(const s16x8*)(Kb + (km << 6) + ((((kk << 1) + half) ^ (km & 7)) << 3));

        // ---- PV(p-1): register-only (hides Ak latency + staging) ----
        __builtin_amdgcn_s_setprio(1);
#pragma unroll
        for (int ksl = 0; ksl < 2; ++ksl) {
            // swap(a,b) -> r.x = a.lo||b.lo (dw-low), r.y = a.hi||b.hi (dw-high)
            u32x2 r0 = __builtin_amdgcn_permlane32_swap(Gh[2*ksl].x, Gh[2*ksl+1].x, false, false);
            u32x2 r1 = __builtin_amdgcn_permlane32_swap(Gh[2*ksl].y, Gh[2*ksl+1].y, false, false);
            CvtU4 ac;
            ac.u.x = r0.x; ac.u.y = r1.x; ac.u.z = r0.y; ac.u.w = r1.y;
            const s16x8 Ap = ac.s;
            O[0] = __builtin_amdgcn_mfma_f32_32x32x16_bf16(Ap, Bvh[2*ksl + 0], O[0], 0, 0, 0);
            O[1] = __builtin_amdgcn_mfma_f32_32x32x16_bf16(Ap, Bvh[2*ksl + 1], O[1], 0, 0, 0);
        }

        // ---- QK quadrant (s,t2) of tile 2p+par ----
        f32x16 S = {0.f,0.f,0.f,0.f,0.f,0.f,0.f,0.f,0.f,0.f,0.f,0.f,0.f,0.f,0.f,0.f};
        S = __builtin_amdgcn_mfma_f32_32x32x16_bf16(Ak[0], Bq[0], S, 0, 0, 0);
        S = __builtin_amdgcn_mfma_f32_32x32x16_bf16(Ak[1], Bq[1], S, 0, 0, 0);
        S = __builtin_amdgcn_mfma_f32_32x32x16_bf16(Ak[2], Bq[2], S, 0, 0, 0);
        S = __builtin_amdgcn_mfma_f32_32x32x16_bf16(Ak[3], Bq[3], S, 0, 0, 0);
        __builtin_amdgcn_s_setprio(0);

        // ---- exp2 + pack -> Gh (consumed next phase) ----
#pragma unroll
        for (int q = 0; q < 4; ++q) {
            float p0 = __builtin_amdgcn_exp2f(S[4*q+0]);
            float p1 = __builtin_amdgcn_exp2f(S[4*q+1]);
            float p2 = __builtin_amdgcn_exp2f(S[4*q+2]);
            float p3 = __builtin_amdgcn_exp2f(S[4*q+3]);
            rs += (p0 + p1) + (p2 + p3);
            Gh[q].x = packbf(p0, p1);
            Gh[q].y = packbf(p2, p3);
        }

        // ---- Bv(p) reads -> held regs (latency merges with barrier drain) ----
        {
            const unsigned short* Vb = &Vl[p & 1][par][0];
#pragma unroll
            for (int ksl = 0; ksl < 2; ++ksl)
#pragma unroll
                for (int dl = 0; dl < 2; ++dl) {
                    const int drow = (dl << 5) + l31;
                    const int cch = (s << 2) + (ksl << 1) + half;
                    Bvh[2*ksl + dl] =
                        *(const s16x8*)(Vb + (drow << 6) + ((cch ^ (drow & 7)) << 3));
                }
        }

        __syncthreads();
    }

    // ---- final PV(31): register-only, before LDS scratch reuse ----
#pragma unroll
    for (int ksl = 0; ksl < 2; ++ksl) {
        u32x2 r0 = __builtin_amdgcn_permlane32_swap(Gh[2*ksl].x, Gh[2*ksl+1].x, false, false);
        u32x2 r1 = __builtin_amdgcn_permlane32_swap(Gh[2*ksl].y, Gh[2*ksl+1].y, false, false);
        CvtU4 ac;
        ac.u.x = r0.x; ac.u.y = r1.x; ac.u.z = r0.y; ac.u.w = r1.y;
        const s16x8 Ap = ac.s;
        O[0] = __builtin_amdgcn_mfma_f32_32x32x16_bf16(Ap, Bvh[2*ksl + 0], O[0], 0, 0, 0);
        O[1] = __builtin_amdgcn_mfma_f32_32x32x16_bf16(Ap, Bvh[2*ksl + 1], O[1], 0, 0, 0);
    }

    // ================= epilogue: par-merge -> s-merge -> store =============
    float* scrK = (float*)&Kl[0][0][0];   // 8192 f32
    float* scrV = (float*)&Vl[0][0][0];   // 8192 f32

    rs += __shfl_xor(rs, 32);
    if (half == 0) rsL[w][l31] = rs;

    if (par == 1) {       // par-merge write: region qd (8 regions x 2048 f32)
        float* rg = (qd < 4) ? (scrK + (qd << 11)) : (scrV + ((qd - 4) << 11));
#pragma unroll
        for (int dl = 0; dl < 2; ++dl)
#pragma unroll
            for (int r = 0; r < 16; ++r)
                rg[(dl << 10) + (r << 6) + lane] = O[dl][r];
    }
    __syncthreads();

    if (tid < 128) {      // denom: 4 contributing waves per n-slab
        int tt = tid >> 5, n32 = tid & 31;
        dnm[tid] = (rsL[(tt << 1) + 0][n32] + rsL[(tt << 1) + 1][n32]) +
                   (rsL[(tt << 1) + 8][n32] + rsL[(tt << 1) + 9][n32]);
    }
    if (par == 0) {       // par-merge read
        float* rg = (qd < 4) ? (scrK + (qd << 11)) : (scrV + ((qd - 4) << 11));
#pragma unroll
        for (int dl = 0; dl < 2; ++dl)
#pragma unroll
            for (int r = 0; r < 16; ++r)
                O[dl][r] += rg[(dl << 10) + (r << 6) + lane];
    }
    __syncthreads();

    if (par == 0 && s == 1) {   // s-merge write: region t2 (4 x 2048 f32 in scrK)
#pragma unroll
        for (int dl = 0; dl < 2; ++dl)
#pragma unroll
            for (int r = 0; r < 16; ++r)
                scrK[(t2 << 11) + (dl << 10) + (r << 6) + lane] = O[dl][r];
    }
    __syncthreads();

    if (par == 0 && s == 0) {
        const int nb = (b << 12) + qbase;
#pragma unroll
        for (int dl = 0; dl < 2; ++dl)
#pragma unroll
            for (int r = 0; r < 16; ++r) {
                int rowoff = (r & 3) + ((r >> 2) << 3) + (half << 2);
                int n = (t2 << 5) + rowoff;
                float o = O[dl][r] + scrK[(t2 << 11) + (dl << 10) + (r << 6) + lane];
                outO[((size_t)(nb + n) << 6) + (dl << 5) + l31] =
                    (unsigned short)f2bf(o * (1.f / dnm[n]));
            }
    }
}

// ---------------------------------------------------------------------------
// k_post v2: w-half split. grid 1024 = (b, h, wh), 256 thr.
// ---------------------------------------------------------------------------
__global__ __launch_bounds__(256) void k_post(
    const unsigned short* __restrict__ Obase,
    const float* __restrict__ x,
    const float* __restrict__ w2,
    const float* __restrict__ g2, const float* __restrict__ b2,
    const float* __restrict__ m2, const float* __restrict__ v2,
    const float* __restrict__ w3,
    const float* __restrict__ g3, const float* __restrict__ b3,
    const float* __restrict__ m3, const float* __restrict__ v3,
    float* __restrict__ out)
{
    __shared__ float W[3][34 * 66];   // [row][col][ch] (+2 pad per col)
    __shared__ float T2[32 * 66];

    const int b  = blockIdx.x >> 7;
    const int h  = (blockIdx.x >> 1) & 63;
    const int wh = blockIdx.x & 1;
    const int wbase = wh << 5;
    const int tid = threadIdx.x;

#pragma unroll
    for (int r = 0; r < 3; ++r) {
        int hh = h + r - 1;
#pragma unroll
        for (int i = 0; i < 2; ++i) {
            int lin = (i << 8) + tid;
            if (lin < 272) {
                int wl = lin >> 3, cg = lin & 7;
                int wg = wbase + wl - 1;
                float* Wd = &W[r][wl * 66 + (cg << 3)];
                if (hh >= 0 && hh <= 63 && wg >= 0 && wg <= 63) {
                    size_t npos = (size_t)((b << 12) + (hh << 6) + wg);
                    uint4 v = *(const uint4*)(Obase + (npos << 6) + (cg << 3));
                    union { float f; unsigned u; } t;
                    t.u = v.x << 16;         Wd[0] = t.f;
                    t.u = v.x & 0xFFFF0000u; Wd[1] = t.f;
                    t.u = v.y << 16;         Wd[2] = t.f;
                    t.u = v.y & 0xFFFF0000u; Wd[3] = t.f;
                    t.u = v.z << 16;         Wd[4] = t.f;
                    t.u = v.z & 0xFFFF0000u; Wd[5] = t.f;
                    t.u = v.w << 16;         Wd[6] = t.f;
                    t.u = v.w & 0xFFFF0000u; Wd[7] = t.f;
                } else {
#pragma unroll
                    for (int j = 0; j < 8; ++j) Wd[j] = 0.f;
                }
            }
        }
    }
    __syncthreads();

    const int w32 = tid & 31, cq = tid >> 5;   // cq in [0,8): 8 channels
    float t8[8];
#pragma unroll
    for (int i = 0; i < 8; ++i) t8[i] = 0.f;

#pragma unroll
    for (int ky = 0; ky < 3; ++ky) {
#pragma unroll
        for (int kx = 0; kx < 3; ++kx) {
            const int k = ky * 3 + kx;
            const float* Wr = &W[ky][(w32 + kx) * 66 + (cq << 3)];
#pragma unroll
            for (int i = 0; i < 2; ++i) {
                float4 a = *(const float4*)(Wr + (i << 2));
                int c = (cq << 3) + (i << 2);
                t8[i * 4 + 0] = fmaf(w2[(c + 0) * 9 + k], a.x, t8[i * 4 + 0]);
                t8[i * 4 + 1] = fmaf(w2[(c + 1) * 9 + k], a.y, t8[i * 4 + 1]);
                t8[i * 4 + 2] = fmaf(w2[(c + 2) * 9 + k], a.z, t8[i * 4 + 2]);
                t8[i * 4 + 3] = fmaf(w2[(c + 3) * 9 + k], a.w, t8[i * 4 + 3]);
            }
        }
    }
#pragma unroll
    for (int i = 0; i < 8; ++i) {
        int c = (cq << 3) + i;
        float inv = g2[c] * rsqrtf(v2[c] + 1e-5f);
        float sh  = b2[c] - m2[c] * inv;
        T2[w32 * 66 + c] = fmaxf(fmaf(t8[i], inv, sh), 0.f);
    }
    __syncthreads();

    float rT[64];
#pragma unroll
    for (int c4 = 0; c4 < 16; ++c4)
        *(float4*)&rT[c4 << 2] = *(const float4*)&T2[w32 * 66 + (c4 << 2)];

    const int hw = (h << 6) + wbase + w32;
#pragma unroll 2
    for (int oo = 0; oo < 8; ++oo) {
        int o = (cq << 3) + oo;
        float inv = g3[o] * rsqrtf(v3[o] + 1e-5f);
        float sh  = b3[o] - m3[o] * inv;
        float acc = 0.f;
#pragma unroll
        for (int c = 0; c < 64; ++c) acc = fmaf(w3[o * 64 + c], rT[c], acc);
        size_t idx = (((size_t)((b << 6) + o)) << 12) + hw;
        out[idx] = fmaf(acc, inv, sh) + x[idx];
    }
}

// ---------------------------------------------------------------------------
extern "C" void kernel_launch(void* const* d_in, const int* in_sizes, int n_in,
                              void* d_out, int out_size, void* d_ws, size_t ws_size,
                              hipStream_t stream)
{
    const float* x  = (const float*)d_in[0];
    const float* w1 = (const float*)d_in[1];
    const float* g1 = (const float*)d_in[2];
    const float* b1 = (const float*)d_in[3];
    const float* m1 = (const float*)d_in[4];
    const float* v1 = (const float*)d_in[5];
    const float* w2 = (const float*)d_in[6];
    const float* g2 = (const float*)d_in[7];
    const float* b2 = (const float*)d_in[8];
    const float* m2 = (const float*)d_in[9];
    const float* v2 = (const float*)d_in[10];
    const float* w3 = (const float*)d_in[11];
    const float* g3 = (const float*)d_in[12];
    const float* b3 = (const float*)d_in[13];
    const float* m3 = (const float*)d_in[14];
    const float* v3 = (const float*)d_in[15];
    float* out = (float*)d_out;

    // ws: xT 4MB | vbf 4MB | O 4MB (bf16, normalized)
    unsigned short* xT  = (unsigned short*)d_ws;
    unsigned short* vbf = xT + (size_t)8 * 4096 * 64;
    unsigned short* Obase = (unsigned short*)((char*)d_ws + (8u << 20));

    k_prep<<<1024, 256, 0, stream>>>(x, w1, g1, b1, m1, v1, xT, vbf);
    k_attn<<<256, 1024, 0, stream>>>(xT, vbf, Obase);
    k_post<<<1024, 256, 0, stream>>>(Obase, x, w2, g2, b2, m2, v2,
                                     w3, g3, b3, m3, v3, out);
}

// Round 9
// 183.697 us; speedup vs baseline: 1.1437x; 1.0021x over previous
//
#include <hip/hip_runtime.h>
#include <stdint.h>

typedef __attribute__((ext_vector_type(8)))  short s16x8;   // 8 x bf16
typedef __attribute__((ext_vector_type(16))) float f32x16;  // 32x32 MFMA acc
typedef __attribute__((ext_vector_type(2)))  unsigned u32x2;

union CvtI4 { int4 i; s16x8 s; };
union CvtU4 { uint4 u; s16x8 s; };

__device__ __forceinline__ unsigned f2bf(float f) {
    union { float f; unsigned u; } v; v.f = f;
    return (v.u + 0x7fffu + ((v.u >> 16) & 1u)) >> 16;     // RNE
}

// pack two f32 -> (bf16(lo) | bf16(hi)<<16), round-half-up (v12-verified idiom)
__device__ __forceinline__ unsigned packbf(float lo, float hi) {
    union { float f; unsigned u; } a0, a1;
    a0.f = lo; a1.f = hi;
    return __builtin_amdgcn_perm(a1.u + 0x8000u, a0.u + 0x8000u, 0x07060302u);
}

__device__ __forceinline__ void gload_lds16(const unsigned short* gsrc, unsigned short* ldst) {
    __builtin_amdgcn_global_load_lds(
        (const __attribute__((address_space(1))) void*)gsrc,
        (__attribute__((address_space(3))) void*)ldst, 16, 0, 0);
}

// ---------------------------------------------------------------------------
// k_prep: grid 1024 = (b, n0-chunk, half). LDS-transpose x tile ->
//   xT[b][n][c] = bf16(x * sqrt(log2e/8)), vbf[b][c][n] = bf16(relu(bn1(w1.x)))
// ---------------------------------------------------------------------------
__global__ __launch_bounds__(256) void k_prep(
    const float* __restrict__ x, const float* __restrict__ w1,
    const float* __restrict__ g1, const float* __restrict__ b1,
    const float* __restrict__ m1, const float* __restrict__ v1,
    unsigned short* __restrict__ xT, unsigned short* __restrict__ vbf)
{
    __shared__ float X[64 * 65];   // [c][n] pad+1
    const int b    = blockIdx.x >> 7;
    const int n0   = ((blockIdx.x >> 1) & 63) << 6;
    const int half = blockIdx.x & 1;
    const int tid  = threadIdx.x;
    const float QS = 0.42466090014400953f;   // sqrt(log2(e)/8)

    {
        const int r = tid >> 6, nn = tid & 63;
        const float* xb = x + (size_t)b * 262144 + n0 + nn;
#pragma unroll
        for (int cc = 0; cc < 16; ++cc) {
            int c = cc * 4 + r;
            X[c * 65 + nn] = xb[(size_t)c * 4096];
        }
    }
    __syncthreads();

    {   // xT: 32 n rows, 8 threads per 128B row
        const int n8 = tid >> 3, c8 = tid & 7;
        const int n = (half << 5) + n8;
        unsigned u[4];
#pragma unroll
        for (int j = 0; j < 4; ++j) {
            unsigned lo = f2bf(X[(c8 * 8 + 2 * j) * 65 + n] * QS);
            unsigned hi = f2bf(X[(c8 * 8 + 2 * j + 1) * 65 + n] * QS);
            u[j] = lo | (hi << 16);
        }
        uint4 pk; pk.x = u[0]; pk.y = u[1]; pk.z = u[2]; pk.w = u[3];
        *(uint4*)(xT + (((size_t)((b << 12) + n0 + n)) << 6) + (c8 << 3)) = pk;
    }

    {   // V = relu(bn1(conv1x1)): 32 output channels for this half
        const int n = tid & 63, og = tid >> 6;
        float rX[64];
#pragma unroll
        for (int c = 0; c < 64; ++c) rX[c] = X[c * 65 + n];
        unsigned short* vb = vbf + (((size_t)(b << 6)) << 12) + n0 + n;
#pragma unroll 2
        for (int oo = 0; oo < 8; ++oo) {
            int o = (half << 5) + og * 8 + oo;
            float inv = g1[o] * rsqrtf(v1[o] + 1e-5f);
            float sh  = b1[o] - m1[o] * inv;
            float acc = 0.f;
#pragma unroll
            for (int c = 0; c < 64; ++c) acc = fmaf(w1[o * 64 + c], rX[c], acc);
            vb[(size_t)o << 12] = (unsigned short)f2bf(fmaxf(fmaf(acc, inv, sh), 0.f));
        }
    }
}

// ---------------------------------------------------------------------------
// k_attn v19: v18 + global_load_lds staging (pre-swizzled SOURCE, linear
// LDS dest -- m173 pattern). LDS content byte-identical to v18: slot
// (sr, j) holds global chunk j^(sr&7), because lane l (row 8(w&7)+(l>>3),
// slot l&7) loads source chunk (l&7)^(l>>3). Per thread per phase the
// {2 global loads + 2 ds_writes + clamp math + 8 VGPR holds} become just
// 2 global_load_lds instructions; end-of-phase __syncthreads drains vmcnt.
// Rest identical to v18: 16 waves (4/SIMD), per-wave v15 quadrant
// (qd = s + 2*t2, par), cross-phase PV in regs (Gh/Bvh), 1 barrier/phase.
// grid 256 = (b=XCD, qg2 of 128 q rows), 1 block/CU.
// ---------------------------------------------------------------------------
__global__ __launch_bounds__(1024, 4) void k_attn(
    const unsigned short* __restrict__ xT, const unsigned short* __restrict__ vbf,
    unsigned short* __restrict__ outO)
{
    __shared__ __align__(16) unsigned short Kl[2][2][64 * 64];  // [buf][pt][m][c] swz8
    __shared__ __align__(16) unsigned short Vl[2][2][64 * 64];  // [buf][pt][d][m] swz8
    __shared__ float rsL[16][32];
    __shared__ float dnm[128];

    const int b   = blockIdx.x & 7;           // batch == XCD slice
    const int qg2 = blockIdx.x >> 3;          // 0..31 (128-q group)
    const int tid = threadIdx.x;
    const int w = tid >> 6, lane = tid & 63;
    const int l31 = lane & 31, half = lane >> 5;
    const int qbase = qg2 << 7;
    const int qd = w & 7, par = w >> 3;
    const int s  = qd & 1;     // m-strip (QK) / PV m-chunk group
    const int t2 = qd >> 1;    // n-slab (0..3), 32 q rows each

    // ---- Q fragments (B operand), rows n = qbase + t2*32 + l31 ----
    s16x8 Bq[4];
    {
        const unsigned short* qr = xT +
            (((size_t)((b << 12) + qbase + (t2 << 5) + l31)) << 6) + (half << 3);
#pragma unroll
        for (int kk = 0; kk < 4; ++kk) {
            CvtI4 c; c.i = *(const int4*)(qr + (kk << 4));
            Bq[kk] = c.s;
        }
    }

    // ---- DMA staging mapping: wave (pt = w>>3) stages rows 8(w&7)..+8 ----
    // of tile pair-member pt; lane l -> row 8(w&7)+(l>>3), source chunk
    // (l&7)^(l>>3) (involution => LDS slot (sr,j) = global chunk j^(sr&7)).
    const int pt    = w >> 3;                 // tile parity this wave stages
    const int sr    = ((w & 7) << 3) + (lane >> 3);
    const int swsc  = (lane & 7) ^ (lane >> 3);
    const unsigned short* kSrc = xT  + ((size_t)b << 18) + (sr << 6) + (swsc << 3);
    const unsigned short* vSrc = vbf + ((size_t)b << 18) + ((size_t)sr << 12) + (swsc << 3);
    const int ldsOff = (w & 7) << 9;          // wave-uniform: 8 rows * 64 ushort

    // ================= prologue: DMA-stage pair 0 =================
    gload_lds16(kSrc + ((size_t)pt << 12), &Kl[0][pt][0] + ldsOff);
    gload_lds16(vSrc + (pt << 6),          &Vl[0][pt][0] + ldsOff);
    __syncthreads();

    f32x16 O[2];
#pragma unroll
    for (int dl = 0; dl < 2; ++dl)
#pragma unroll
        for (int r = 0; r < 16; ++r) O[dl][r] = 0.f;
    float rs = 0.f;

    // cross-phase holds (zero for phase 0: 0x0 MFMA contributes nothing)
    uint2 Gh[4];
    s16x8 Bvh[4];
    {
        const s16x8 z = {0, 0, 0, 0, 0, 0, 0, 0};
#pragma unroll
        for (int q = 0; q < 4; ++q) { Gh[q].x = 0u; Gh[q].y = 0u; }
#pragma unroll
        for (int j = 0; j < 4; ++j) Bvh[j] = z;
    }

    const int km = (s << 5) + l31;

    // ================= main loop: 32 phases, 1 barrier each =================
    for (int p = 0; p < 32; ++p) {
        // DMA-stage pair p+1 into buf[(p+1)&1] (skip on last phase)
        if (p < 31) {
            const int tn = ((p + 1) << 1) + pt;
            gload_lds16(kSrc + ((size_t)tn << 12), &Kl[(p + 1) & 1][pt][0] + ldsOff);
            gload_lds16(vSrc + (tn << 6),          &Vl[(p + 1) & 1][pt][0] + ldsOff);
        }

        // ---- issue Ak ds_reads for QK(p) ----
        const unsigned short* Kb = &Kl[p & 1][par][0];
        s16x8 Ak[4];
#pragma unroll
        for (int kk = 0; kk < 4; ++kk)
            Ak[kk] = *(const s16x8*)(Kb + (km << 6) + ((((kk << 1) + half) ^ (km & 7)) << 3));

        // ---- PV(p-1): register-only (hides Ak latency + staging) ----
        __builtin_amdgcn_s_setprio(1);
#pragma unroll
        for (int ksl = 0; ksl < 2; ++ksl) {
            // swap(a,b) -> r.x = a.lo||b.lo (dw-low), r.y = a.hi||b.hi (dw-high)
            u32x2 r0 = __builtin_amdgcn_permlane32_swap(Gh[2*ksl].x, Gh[2*ksl+1].x, false, false);
            u32x2 r1 = __builtin_amdgcn_permlane32_swap(Gh[2*ksl].y, Gh[2*ksl+1].y, false, false);
            CvtU4 ac;
            ac.u.x = r0.x; ac.u.y = r1.x; ac.u.z = r0.y; ac.u.w = r1.y;
            const s16x8 Ap = ac.s;
            O[0] = __builtin_amdgcn_mfma_f32_32x32x16_bf16(Ap, Bvh[0 + 2*ksl], O[0], 0, 0, 0);
            O[1] = __builtin_amdgcn_mfma_f32_32x32x16_bf16(Ap, Bvh[1 + 2*ksl], O[1], 0, 0, 0);
        }

        // ---- QK quadrant (s,t2) of tile 2p+par ----
        f32x16 S = {0.f,0.f,0.f,0.f,0.f,0.f,0.f,0.f,0.f,0.f,0.f,0.f,0.f,0.f,0.f,0.f};
        S = __builtin_amdgcn_mfma_f32_32x32x16_bf16(Ak[0], Bq[0], S, 0, 0, 0);
        S = __builtin_amdgcn_mfma_f32_32x32x16_bf16(Ak[1], Bq[1], S, 0, 0, 0);
        S = __builtin_amdgcn_mfma_f32_32x32x16_bf16(Ak[2], Bq[2], S, 0, 0, 0);
        S = __builtin_amdgcn_mfma_f32_32x32x16_bf16(Ak[3], Bq[3], S, 0, 0, 0);
        __builtin_amdgcn_s_setprio(0);

        // ---- exp2 + pack -> Gh (consumed next phase) ----
#pragma unroll
        for (int q = 0; q < 4; ++q) {
            float p0 = __builtin_amdgcn_exp2f(S[4*q+0]);
            float p1 = __builtin_amdgcn_exp2f(S[4*q+1]);
            float p2 = __builtin_amdgcn_exp2f(S[4*q+2]);
            float p3 = __builtin_amdgcn_exp2f(S[4*q+3]);
            rs += (p0 + p1) + (p2 + p3);
            Gh[q].x = packbf(p0, p1);
            Gh[q].y = packbf(p2, p3);
        }

        // ---- Bv(p) reads -> held regs (latency merges with barrier drain) ----
        {
            const unsigned short* Vb = &Vl[p & 1][par][0];
#pragma unroll
            for (int ksl = 0; ksl < 2; ++ksl)
#pragma unroll
                for (int dl = 0; dl < 2; ++dl) {
                    const int drow = (dl << 5) + l31;
                    const int cch = (s << 2) + (ksl << 1) + half;
                    Bvh[2*ksl + dl] =
                        *(const s16x8*)(Vb + (drow << 6) + ((cch ^ (drow & 7)) << 3));
                }
        }

        __syncthreads();
    }

    // ---- final PV(31): register-only, before LDS scratch reuse ----
#pragma unroll
    for (int ksl = 0; ksl < 2; ++ksl) {
        u32x2 r0 = __builtin_amdgcn_permlane32_swap(Gh[2*ksl].x, Gh[2*ksl+1].x, false, false);
        u32x2 r1 = __builtin_amdgcn_permlane32_swap(Gh[2*ksl].y, Gh[2*ksl+1].y, false, false);
        CvtU4 ac;
        ac.u.x = r0.x; ac.u.y = r1.x; ac.u.z = r0.y; ac.u.w = r1.y;
        const s16x8 Ap = ac.s;
        O[0] = __builtin_amdgcn_mfma_f32_32x32x16_bf16(Ap, Bvh[0 + 2*ksl], O[0], 0, 0, 0);
        O[1] = __builtin_amdgcn_mfma_f32_32x32x16_bf16(Ap, Bvh[1 + 2*ksl], O[1], 0, 0, 0);
    }

    // ================= epilogue: par-merge -> s-merge -> store =============
    float* scrK = (float*)&Kl[0][0][0];   // 8192 f32
    float* scrV = (float*)&Vl[0][0][0];   // 8192 f32

    rs += __shfl_xor(rs, 32);
    if (half == 0) rsL[w][l31] = rs;

    if (par == 1) {       // par-merge write: region qd (8 regions x 2048 f32)
        float* rg = (qd < 4) ? (scrK + (qd << 11)) : (scrV + ((qd - 4) << 11));
#pragma unroll
        for (int dl = 0; dl < 2; ++dl)
#pragma unroll
            for (int r = 0; r < 16; ++r)
                rg[(dl << 10) + (r << 6) + lane] = O[dl][r];
    }
    __syncthreads();

    if (tid < 128) {      // denom: 4 contributing waves per n-slab
        int tt = tid >> 5, n32 = tid & 31;
        dnm[tid] = (rsL[(tt << 1) + 0][n32] + rsL[(tt << 1) + 1][n32]) +
                   (rsL[(tt << 1) + 8][n32] + rsL[(tt << 1) + 9][n32]);
    }
    if (par == 0) {       // par-merge read
        float* rg = (qd < 4) ? (scrK + (qd << 11)) : (scrV + ((qd - 4) << 11));
#pragma unroll
        for (int dl = 0; dl < 2; ++dl)
#pragma unroll
            for (int r = 0; r < 16; ++r)
                O[dl][r] += rg[(dl << 10) + (r << 6) + lane];
    }
    __syncthreads();

    if (par == 0 && s == 1) {   // s-merge write: region t2 (4 x 2048 f32 in scrK)
#pragma unroll
        for (int dl = 0; dl < 2; ++dl)
#pragma unroll
            for (int r = 0; r < 16; ++r)
                scrK[(t2 << 11) + (dl << 10) + (r << 6) + lane] = O[dl][r];
    }
    __syncthreads();

    if (par == 0 && s == 0) {
        const int nb = (b << 12) + qbase;
#pragma unroll
        for (int dl = 0; dl < 2; ++dl)
#pragma unroll
            for (int r = 0; r < 16; ++r) {
                int rowoff = (r & 3) + ((r >> 2) << 3) + (half << 2);
                int n = (t2 << 5) + rowoff;
                float o = O[dl][r] + scrK[(t2 << 11) + (dl << 10) + (r << 6) + lane];
                outO[((size_t)(nb + n) << 6) + (dl << 5) + l31] =
                    (unsigned short)f2bf(o * (1.f / dnm[n]));
            }
    }
}

// ---------------------------------------------------------------------------
// k_post v2: w-half split. grid 1024 = (b, h, wh), 256 thr.
// ---------------------------------------------------------------------------
__global__ __launch_bounds__(256) void k_post(
    const unsigned short* __restrict__ Obase,
    const float* __restrict__ x,
    const float* __restrict__ w2,
    const float* __restrict__ g2, const float* __restrict__ b2,
    const float* __restrict__ m2, const float* __restrict__ v2,
    const float* __restrict__ w3,
    const float* __restrict__ g3, const float* __restrict__ b3,
    const float* __restrict__ m3, const float* __restrict__ v3,
    float* __restrict__ out)
{
    __shared__ float W[3][34 * 66];   // [row][col][ch] (+2 pad per col)
    __shared__ float T2[32 * 66];

    const int b  = blockIdx.x >> 7;
    const int h  = (blockIdx.x >> 1) & 63;
    const int wh = blockIdx.x & 1;
    const int wbase = wh << 5;
    const int tid = threadIdx.x;

#pragma unroll
    for (int r = 0; r < 3; ++r) {
        int hh = h + r - 1;
#pragma unroll
        for (int i = 0; i < 2; ++i) {
            int lin = (i << 8) + tid;
            if (lin < 272) {
                int wl = lin >> 3, cg = lin & 7;
                int wg = wbase + wl - 1;
                float* Wd = &W[r][wl * 66 + (cg << 3)];
                if (hh >= 0 && hh <= 63 && wg >= 0 && wg <= 63) {
                    size_t npos = (size_t)((b << 12) + (hh << 6) + wg);
                    uint4 v = *(const uint4*)(Obase + (npos << 6) + (cg << 3));
                    union { float f; unsigned u; } t;
                    t.u = v.x << 16;         Wd[0] = t.f;
                    t.u = v.x & 0xFFFF0000u; Wd[1] = t.f;
                    t.u = v.y << 16;         Wd[2] = t.f;
                    t.u = v.y & 0xFFFF0000u; Wd[3] = t.f;
                    t.u = v.z << 16;         Wd[4] = t.f;
                    t.u = v.z & 0xFFFF0000u; Wd[5] = t.f;
                    t.u = v.w << 16;         Wd[6] = t.f;
                    t.u = v.w & 0xFFFF0000u; Wd[7] = t.f;
                } else {
#pragma unroll
                    for (int j = 0; j < 8; ++j) Wd[j] = 0.f;
                }
            }
        }
    }
    __syncthreads();

    const int w32 = tid & 31, cq = tid >> 5;   // cq in [0,8): 8 channels
    float t8[8];
#pragma unroll
    for (int i = 0; i < 8; ++i) t8[i] = 0.f;

#pragma unroll
    for (int ky = 0; ky < 3; ++ky) {
#pragma unroll
        for (int kx = 0; kx < 3; ++kx) {
            const int k = ky * 3 + kx;
            const float* Wr = &W[ky][(w32 + kx) * 66 + (cq << 3)];
#pragma unroll
            for (int i = 0; i < 2; ++i) {
                float4 a = *(const float4*)(Wr + (i << 2));
                int c = (cq << 3) + (i << 2);
                t8[i * 4 + 0] = fmaf(w2[(c + 0) * 9 + k], a.x, t8[i * 4 + 0]);
                t8[i * 4 + 1] = fmaf(w2[(c + 1) * 9 + k], a.y, t8[i * 4 + 1]);
                t8[i * 4 + 2] = fmaf(w2[(c + 2) * 9 + k], a.z, t8[i * 4 + 2]);
                t8[i * 4 + 3] = fmaf(w2[(c + 3) * 9 + k], a.w, t8[i * 4 + 3]);
            }
        }
    }
#pragma unroll
    for (int i = 0; i < 8; ++i) {
        int c = (cq << 3) + i;
        float inv = g2[c] * rsqrtf(v2[c] + 1e-5f);
        float sh  = b2[c] - m2[c] * inv;
        T2[w32 * 66 + c] = fmaxf(fmaf(t8[i], inv, sh), 0.f);
    }
    __syncthreads();

    float rT[64];
#pragma unroll
    for (int c4 = 0; c4 < 16; ++c4)
        *(float4*)&rT[c4 << 2] = *(const float4*)&T2[w32 * 66 + (c4 << 2)];

    const int hw = (h << 6) + wbase + w32;
#pragma unroll 2
    for (int oo = 0; oo < 8; ++oo) {
        int o = (cq << 3) + oo;
        float inv = g3[o] * rsqrtf(v3[o] + 1e-5f);
        float sh  = b3[o] - m3[o] * inv;
        float acc = 0.f;
#pragma unroll
        for (int c = 0; c < 64; ++c) acc = fmaf(w3[o * 64 + c], rT[c], acc);
        size_t idx = (((size_t)((b << 6) + o)) << 12) + hw;
        out[idx] = fmaf(acc, inv, sh) + x[idx];
    }
}

// ---------------------------------------------------------------------------
extern "C" void kernel_launch(void* const* d_in, const int* in_sizes, int n_in,
                              void* d_out, int out_size, void* d_ws, size_t ws_size,
                              hipStream_t stream)
{
    const float* x  = (const float*)d_in[0];
    const float* w1 = (const float*)d_in[1];
    const float* g1 = (const float*)d_in[2];
    const float* b1 = (const float*)d_in[3];
    const float* m1 = (const float*)d_in[4];
    const float* v1 = (const float*)d_in[5];
    const float* w2 = (const float*)d_in[6];
    const float* g2 = (const float*)d_in[7];
    const float* b2 = (const float*)d_in[8];
    const float* m2 = (const float*)d_in[9];
    const float* v2 = (const float*)d_in[10];
    const float* w3 = (const float*)d_in[11];
    const float* g3 = (const float*)d_in[12];
    const float* b3 = (const float*)d_in[13];
    const float* m3 = (const float*)d_in[14];
    const float* v3 = (const float*)d_in[15];
    float* out = (float*)d_out;

    // ws: xT 4MB | vbf 4MB | O 4MB (bf16, normalized)
    unsigned short* xT  = (unsigned short*)d_ws;
    unsigned short* vbf = xT + (size_t)8 * 4096 * 64;
    unsigned short* Obase = (unsigned short*)((char*)d_ws + (8u << 20));

    k_prep<<<1024, 256, 0, stream>>>(x, w1, g1, b1, m1, v1, xT, vbf);
    k_attn<<<256, 1024, 0, stream>>>(xT, vbf, Obase);
    k_post<<<1024, 256, 0, stream>>>(Obase, x, w2, g2, b2, m2, v2,
                                     w3, g3, b3, m3, v3, out);
}

// Round 10
// 183.275 us; speedup vs baseline: 1.1463x; 1.0023x over previous
//
#include <hip/hip_runtime.h>
#include <stdint.h>

typedef __attribute__((ext_vector_type(8)))  short s16x8;   // 8 x bf16
typedef __attribute__((ext_vector_type(16))) float f32x16;  // 32x32 MFMA acc
typedef __attribute__((ext_vector_type(2)))  unsigned u32x2;

union CvtI4 { int4 i; s16x8 s; };
union CvtU4 { uint4 u; s16x8 s; };

__device__ __forceinline__ unsigned f2bf(float f) {
    union { float f; unsigned u; } v; v.f = f;
    return (v.u + 0x7fffu + ((v.u >> 16) & 1u)) >> 16;     // RNE
}

// pack two f32 -> (bf16(lo) | bf16(hi)<<16), round-half-up (v12-verified idiom)
__device__ __forceinline__ unsigned packbf(float lo, float hi) {
    union { float f; unsigned u; } a0, a1;
    a0.f = lo; a1.f = hi;
    return __builtin_amdgcn_perm(a1.u + 0x8000u, a0.u + 0x8000u, 0x07060302u);
}

__device__ __forceinline__ void gload_lds16(const unsigned short* gsrc, unsigned short* ldst) {
    __builtin_amdgcn_global_load_lds(
        (const __attribute__((address_space(1))) void*)gsrc,
        (__attribute__((address_space(3))) void*)ldst, 16, 0, 0);
}

// ---------------------------------------------------------------------------
// k_prep: grid 1024 = (b, n0-chunk, half). LDS-transpose x tile ->
//   xT[b][n][c] = bf16(x * sqrt(log2e/8)), vbf[b][c][n] = bf16(relu(bn1(w1.x)))
// ---------------------------------------------------------------------------
__global__ __launch_bounds__(256) void k_prep(
    const float* __restrict__ x, const float* __restrict__ w1,
    const float* __restrict__ g1, const float* __restrict__ b1,
    const float* __restrict__ m1, const float* __restrict__ v1,
    unsigned short* __restrict__ xT, unsigned short* __restrict__ vbf)
{
    __shared__ float X[64 * 65];   // [c][n] pad+1
    const int b    = blockIdx.x >> 7;
    const int n0   = ((blockIdx.x >> 1) & 63) << 6;
    const int half = blockIdx.x & 1;
    const int tid  = threadIdx.x;
    const float QS = 0.42466090014400953f;   // sqrt(log2(e)/8)

    {
        const int r = tid >> 6, nn = tid & 63;
        const float* xb = x + (size_t)b * 262144 + n0 + nn;
#pragma unroll
        for (int cc = 0; cc < 16; ++cc) {
            int c = cc * 4 + r;
            X[c * 65 + nn] = xb[(size_t)c * 4096];
        }
    }
    __syncthreads();

    {   // xT: 32 n rows, 8 threads per 128B row
        const int n8 = tid >> 3, c8 = tid & 7;
        const int n = (half << 5) + n8;
        unsigned u[4];
#pragma unroll
        for (int j = 0; j < 4; ++j) {
            unsigned lo = f2bf(X[(c8 * 8 + 2 * j) * 65 + n] * QS);
            unsigned hi = f2bf(X[(c8 * 8 + 2 * j + 1) * 65 + n] * QS);
            u[j] = lo | (hi << 16);
        }
        uint4 pk; pk.x = u[0]; pk.y = u[1]; pk.z = u[2]; pk.w = u[3];
        *(uint4*)(xT + (((size_t)((b << 12) + n0 + n)) << 6) + (c8 << 3)) = pk;
    }

    {   // V = relu(bn1(conv1x1)): 32 output channels for this half
        const int n = tid & 63, og = tid >> 6;
        float rX[64];
#pragma unroll
        for (int c = 0; c < 64; ++c) rX[c] = X[c * 65 + n];
        unsigned short* vb = vbf + (((size_t)(b << 6)) << 12) + n0 + n;
#pragma unroll 2
        for (int oo = 0; oo < 8; ++oo) {
            int o = (half << 5) + og * 8 + oo;
            float inv = g1[o] * rsqrtf(v1[o] + 1e-5f);
            float sh  = b1[o] - m1[o] * inv;
            float acc = 0.f;
#pragma unroll
            for (int c = 0; c < 64; ++c) acc = fmaf(w1[o * 64 + c], rX[c], acc);
            vb[(size_t)o << 12] = (unsigned short)f2bf(fmaxf(fmaf(acc, inv, sh), 0.f));
        }
    }
}

// ---------------------------------------------------------------------------
// k_attn v20: v19 + 4-tile phases (16 barriers instead of 32).
// R9 lesson: removing staging issue-work was NULL -> phases are stall-bound
// on the per-phase fixed cost (barrier drain/convergence), not issue-bound.
// v20 halves phase count: LDS [2][4] K+V buffers (128KB, 1 block/CU; grid
// is 256 = 1 block/CU anyway). Per phase each wave runs TWO back-to-back
// tile-jobs (tiles 4p+par, 4p+par+2), each job = v19's verbatim body
// (cross-phase Gh/Bvh register PV pipeline); no barrier between jobs, so
// job-B's Ak ds_reads overlap job-A's exp2/pack. DMA staging: wave w,
// load i: li=2w+i -> tile jt=li>>3, row-group rg=li&7; lane l stages row
// 8rg+(l>>3), pre-swizzled source chunk (l&7)^(l>>3) -> LDS content
// byte-identical to v19. Tiles 4(p+1)+jt <= 63: no tail clamp.
// grid 256 = (b=XCD, qg2 of 128 q rows), 1024 thr.
// ---------------------------------------------------------------------------
__global__ __launch_bounds__(1024, 4) void k_attn(
    const unsigned short* __restrict__ xT, const unsigned short* __restrict__ vbf,
    unsigned short* __restrict__ outO)
{
    __shared__ __align__(16) unsigned short Kl[2][4][64 * 64];  // [buf][j][m][c] swz8
    __shared__ __align__(16) unsigned short Vl[2][4][64 * 64];  // [buf][j][d][m] swz8
    __shared__ float rsL[16][32];
    __shared__ float dnm[128];

    const int b   = blockIdx.x & 7;           // batch == XCD slice
    const int qg2 = blockIdx.x >> 3;          // 0..31 (128-q group)
    const int tid = threadIdx.x;
    const int w = tid >> 6, lane = tid & 63;
    const int l31 = lane & 31, half = lane >> 5;
    const int qbase = qg2 << 7;
    const int qd = w & 7, par = w >> 3;
    const int s  = qd & 1;     // m-strip (QK) / PV m-chunk group
    const int t2 = qd >> 1;    // n-slab (0..3), 32 q rows each

    // ---- Q fragments (B operand), rows n = qbase + t2*32 + l31 ----
    s16x8 Bq[4];
    {
        const unsigned short* qr = xT +
            (((size_t)((b << 12) + qbase + (t2 << 5) + l31)) << 6) + (half << 3);
#pragma unroll
        for (int kk = 0; kk < 4; ++kk) {
            CvtI4 c; c.i = *(const int4*)(qr + (kk << 4));
            Bq[kk] = c.s;
        }
    }

    // ---- DMA staging mapping: load i of wave w -> li=2w+i; tile jt=li>>3,
    // row-group rg=li&7 (rows 8rg..8rg+7); lane l: row 8rg+(l>>3), source
    // chunk (l&7)^(l>>3). Involution => LDS slot (sr,j) = chunk j^(sr&7).
    int jt_[2], rg_[2];
    {
        int li0 = (w << 1), li1 = (w << 1) + 1;
        jt_[0] = li0 >> 3; rg_[0] = li0 & 7;
        jt_[1] = li1 >> 3; rg_[1] = li1 & 7;
    }
    const int lrow = lane >> 3;                  // 0..7 within row-group
    const int swsc = (lane & 7) ^ lrow;          // pre-swizzled chunk
    const unsigned short* kRow0 = xT  + ((size_t)b << 18) + (((rg_[0] << 3) + lrow) << 6) + (swsc << 3);
    const unsigned short* kRow1 = xT  + ((size_t)b << 18) + (((rg_[1] << 3) + lrow) << 6) + (swsc << 3);
    const unsigned short* vRow0 = vbf + ((size_t)b << 18) + ((size_t)((rg_[0] << 3) + lrow) << 12) + (swsc << 3);
    const unsigned short* vRow1 = vbf + ((size_t)b << 18) + ((size_t)((rg_[1] << 3) + lrow) << 12) + (swsc << 3);
    const int ldsOff0 = rg_[0] << 9;             // wave-uniform: 8 rows * 64 ushort
    const int ldsOff1 = rg_[1] << 9;

    // ================= prologue: DMA-stage tiles 0..3 =================
    gload_lds16(kRow0 + ((size_t)jt_[0] << 12), &Kl[0][jt_[0]][0] + ldsOff0);
    gload_lds16(kRow1 + ((size_t)jt_[1] << 12), &Kl[0][jt_[1]][0] + ldsOff1);
    gload_lds16(vRow0 + (jt_[0] << 6),          &Vl[0][jt_[0]][0] + ldsOff0);
    gload_lds16(vRow1 + (jt_[1] << 6),          &Vl[0][jt_[1]][0] + ldsOff1);
    __syncthreads();

    f32x16 O[2];
#pragma unroll
    for (int dl = 0; dl < 2; ++dl)
#pragma unroll
        for (int r = 0; r < 16; ++r) O[dl][r] = 0.f;
    float rs = 0.f;

    // cross-job holds (zero initially: 0x0 MFMA contributes nothing)
    uint2 Gh[4];
    s16x8 Bvh[4];
    {
        const s16x8 z = {0, 0, 0, 0, 0, 0, 0, 0};
#pragma unroll
        for (int q = 0; q < 4; ++q) { Gh[q].x = 0u; Gh[q].y = 0u; }
#pragma unroll
        for (int j = 0; j < 4; ++j) Bvh[j] = z;
    }

    const int km = (s << 5) + l31;

    // ================= main loop: 16 phases, 1 barrier each =================
    for (int p = 0; p < 16; ++p) {
        // DMA-stage phase p+1's 4 tiles into buf[(p+1)&1] (skip last phase)
        if (p < 15) {
            const int t0 = ((p + 1) << 2) + jt_[0];
            const int t1 = ((p + 1) << 2) + jt_[1];
            gload_lds16(kRow0 + ((size_t)t0 << 12), &Kl[(p + 1) & 1][jt_[0]][0] + ldsOff0);
            gload_lds16(kRow1 + ((size_t)t1 << 12), &Kl[(p + 1) & 1][jt_[1]][0] + ldsOff1);
            gload_lds16(vRow0 + (t0 << 6),          &Vl[(p + 1) & 1][jt_[0]][0] + ldsOff0);
            gload_lds16(vRow1 + (t1 << 6),          &Vl[(p + 1) & 1][jt_[1]][0] + ldsOff1);
        }

        // ---- two tile-jobs: j = par, par+2 (tiles 4p+j) ----
#pragma unroll
        for (int jj = 0; jj < 2; ++jj) {
            const int j = par + (jj << 1);

            // issue Ak ds_reads for QK(this job)
            const unsigned short* Kb = &Kl[p & 1][j][0];
            s16x8 Ak[4];
#pragma unroll
            for (int kk = 0; kk < 4; ++kk)
                Ak[kk] = *(const s16x8*)(Kb + (km << 6) + ((((kk << 1) + half) ^ (km & 7)) << 3));

            // PV(previous job): register-only (hides Ak latency + staging)
            __builtin_amdgcn_s_setprio(1);
#pragma unroll
            for (int ksl = 0; ksl < 2; ++ksl) {
                // swap(a,b) -> r.x = a.lo||b.lo (dw-low), r.y = a.hi||b.hi (dw-high)
                u32x2 r0 = __builtin_amdgcn_permlane32_swap(Gh[2*ksl].x, Gh[2*ksl+1].x, false, false);
                u32x2 r1 = __builtin_amdgcn_permlane32_swap(Gh[2*ksl].y, Gh[2*ksl+1].y, false, false);
                CvtU4 ac;
                ac.u.x = r0.x; ac.u.y = r1.x; ac.u.z = r0.y; ac.u.w = r1.y;
                const s16x8 Ap = ac.s;
                O[0] = __builtin_amdgcn_mfma_f32_32x32x16_bf16(Ap, Bvh[0 + 2*ksl], O[0], 0, 0, 0);
                O[1] = __builtin_amdgcn_mfma_f32_32x32x16_bf16(Ap, Bvh[1 + 2*ksl], O[1], 0, 0, 0);
            }

            // QK quadrant (s,t2) of tile 4p+j
            f32x16 S = {0.f,0.f,0.f,0.f,0.f,0.f,0.f,0.f,0.f,0.f,0.f,0.f,0.f,0.f,0.f,0.f};
            S = __builtin_amdgcn_mfma_f32_32x32x16_bf16(Ak[0], Bq[0], S, 0, 0, 0);
            S = __builtin_amdgcn_mfma_f32_32x32x16_bf16(Ak[1], Bq[1], S, 0, 0, 0);
            S = __builtin_amdgcn_mfma_f32_32x32x16_bf16(Ak[2], Bq[2], S, 0, 0, 0);
            S = __builtin_amdgcn_mfma_f32_32x32x16_bf16(Ak[3], Bq[3], S, 0, 0, 0);
            __builtin_amdgcn_s_setprio(0);

            // exp2 + pack -> Gh (consumed by next job's PV)
#pragma unroll
            for (int q = 0; q < 4; ++q) {
                float p0 = __builtin_amdgcn_exp2f(S[4*q+0]);
                float p1 = __builtin_amdgcn_exp2f(S[4*q+1]);
                float p2 = __builtin_amdgcn_exp2f(S[4*q+2]);
                float p3 = __builtin_amdgcn_exp2f(S[4*q+3]);
                rs += (p0 + p1) + (p2 + p3);
                Gh[q].x = packbf(p0, p1);
                Gh[q].y = packbf(p2, p3);
            }

            // Bv(this job) reads -> held regs (buffer valid until phase barrier)
            {
                const unsigned short* Vb = &Vl[p & 1][j][0];
#pragma unroll
                for (int ksl = 0; ksl < 2; ++ksl)
#pragma unroll
                    for (int dl = 0; dl < 2; ++dl) {
                        const int drow = (dl << 5) + l31;
                        const int cch = (s << 2) + (ksl << 1) + half;
                        Bvh[2*ksl + dl] =
                            *(const s16x8*)(Vb + (drow << 6) + ((cch ^ (drow & 7)) << 3));
                    }
            }
        }

        __syncthreads();
    }

    // ---- final PV (last held job): register-only, before LDS scratch reuse ----
#pragma unroll
    for (int ksl = 0; ksl < 2; ++ksl) {
        u32x2 r0 = __builtin_amdgcn_permlane32_swap(Gh[2*ksl].x, Gh[2*ksl+1].x, false, false);
        u32x2 r1 = __builtin_amdgcn_permlane32_swap(Gh[2*ksl].y, Gh[2*ksl+1].y, false, false);
        CvtU4 ac;
        ac.u.x = r0.x; ac.u.y = r1.x; ac.u.z = r0.y; ac.u.w = r1.y;
        const s16x8 Ap = ac.s;
        O[0] = __builtin_amdgcn_mfma_f32_32x32x16_bf16(Ap, Bvh[0 + 2*ksl], O[0], 0, 0, 0);
        O[1] = __builtin_amdgcn_mfma_f32_32x32x16_bf16(Ap, Bvh[1 + 2*ksl], O[1], 0, 0, 0);
    }

    // ================= epilogue: par-merge -> s-merge -> store =============
    float* scrK = (float*)&Kl[0][0][0];
    float* scrV = (float*)&Vl[0][0][0];

    rs += __shfl_xor(rs, 32);
    if (half == 0) rsL[w][l31] = rs;

    if (par == 1) {       // par-merge write: region qd (8 regions x 2048 f32)
        float* rg = (qd < 4) ? (scrK + (qd << 11)) : (scrV + ((qd - 4) << 11));
#pragma unroll
        for (int dl = 0; dl < 2; ++dl)
#pragma unroll
            for (int r = 0; r < 16; ++r)
                rg[(dl << 10) + (r << 6) + lane] = O[dl][r];
    }
    __syncthreads();

    if (tid < 128) {      // denom: 4 contributing waves per n-slab
        int tt = tid >> 5, n32 = tid & 31;
        dnm[tid] = (rsL[(tt << 1) + 0][n32] + rsL[(tt << 1) + 1][n32]) +
                   (rsL[(tt << 1) + 8][n32] + rsL[(tt << 1) + 9][n32]);
    }
    if (par == 0) {       // par-merge read
        float* rg = (qd < 4) ? (scrK + (qd << 11)) : (scrV + ((qd - 4) << 11));
#pragma unroll
        for (int dl = 0; dl < 2; ++dl)
#pragma unroll
            for (int r = 0; r < 16; ++r)
                O[dl][r] += rg[(dl << 10) + (r << 6) + lane];
    }
    __syncthreads();

    if (par == 0 && s == 1) {   // s-merge write: region t2 (4 x 2048 f32 in scrK)
#pragma unroll
        for (int dl = 0; dl < 2; ++dl)
#pragma unroll
            for (int r = 0; r < 16; ++r)
                scrK[(t2 << 11) + (dl << 10) + (r << 6) + lane] = O[dl][r];
    }
    __syncthreads();

    if (par == 0 && s == 0) {
        const int nb = (b << 12) + qbase;
#pragma unroll
        for (int dl = 0; dl < 2; ++dl)
#pragma unroll
            for (int r = 0; r < 16; ++r) {
                int rowoff = (r & 3) + ((r >> 2) << 3) + (half << 2);
                int n = (t2 << 5) + rowoff;
                float o = O[dl][r] + scrK[(t2 << 11) + (dl << 10) + (r << 6) + lane];
                outO[((size_t)(nb + n) << 6) + (dl << 5) + l31] =
                    (unsigned short)f2bf(o * (1.f / dnm[n]));
            }
    }
}

// ---------------------------------------------------------------------------
// k_post v2: w-half split. grid 1024 = (b, h, wh), 256 thr.
// ---------------------------------------------------------------------------
__global__ __launch_bounds__(256) void k_post(
    const unsigned short* __restrict__ Obase,
    const float* __restrict__ x,
    const float* __restrict__ w2,
    const float* __restrict__ g2, const float* __restrict__ b2,
    const float* __restrict__ m2, const float* __restrict__ v2,
    const float* __restrict__ w3,
    const float* __restrict__ g3, const float* __restrict__ b3,
    const float* __restrict__ m3, const float* __restrict__ v3,
    float* __restrict__ out)
{
    __shared__ float W[3][34 * 66];   // [row][col][ch] (+2 pad per col)
    __shared__ float T2[32 * 66];

    const int b  = blockIdx.x >> 7;
    const int h  = (blockIdx.x >> 1) & 63;
    const int wh = blockIdx.x & 1;
    const int wbase = wh << 5;
    const int tid = threadIdx.x;

#pragma unroll
    for (int r = 0; r < 3; ++r) {
        int hh = h + r - 1;
#pragma unroll
        for (int i = 0; i < 2; ++i) {
            int lin = (i << 8) + tid;
            if (lin < 272) {
                int wl = lin >> 3, cg = lin & 7;
                int wg = wbase + wl - 1;
                float* Wd = &W[r][wl * 66 + (cg << 3)];
                if (hh >= 0 && hh <= 63 && wg >= 0 && wg <= 63) {
                    size_t npos = (size_t)((b << 12) + (hh << 6) + wg);
                    uint4 v = *(const uint4*)(Obase + (npos << 6) + (cg << 3));
                    union { float f; unsigned u; } t;
                    t.u = v.x << 16;         Wd[0] = t.f;
                    t.u = v.x & 0xFFFF0000u; Wd[1] = t.f;
                    t.u = v.y << 16;         Wd[2] = t.f;
                    t.u = v.y & 0xFFFF0000u; Wd[3] = t.f;
                    t.u = v.z << 16;         Wd[4] = t.f;
                    t.u = v.z & 0xFFFF0000u; Wd[5] = t.f;
                    t.u = v.w << 16;         Wd[6] = t.f;
                    t.u = v.w & 0xFFFF0000u; Wd[7] = t.f;
                } else {
#pragma unroll
                    for (int j = 0; j < 8; ++j) Wd[j] = 0.f;
                }
            }
        }
    }
    __syncthreads();

    const int w32 = tid & 31, cq = tid >> 5;   // cq in [0,8): 8 channels
    float t8[8];
#pragma unroll
    for (int i = 0; i < 8; ++i) t8[i] = 0.f;

#pragma unroll
    for (int ky = 0; ky < 3; ++ky) {
#pragma unroll
        for (int kx = 0; kx < 3; ++kx) {
            const int k = ky * 3 + kx;
            const float* Wr = &W[ky][(w32 + kx) * 66 + (cq << 3)];
#pragma unroll
            for (int i = 0; i < 2; ++i) {
                float4 a = *(const float4*)(Wr + (i << 2));
                int c = (cq << 3) + (i << 2);
                t8[i * 4 + 0] = fmaf(w2[(c + 0) * 9 + k], a.x, t8[i * 4 + 0]);
                t8[i * 4 + 1] = fmaf(w2[(c + 1) * 9 + k], a.y, t8[i * 4 + 1]);
                t8[i * 4 + 2] = fmaf(w2[(c + 2) * 9 + k], a.z, t8[i * 4 + 2]);
                t8[i * 4 + 3] = fmaf(w2[(c + 3) * 9 + k], a.w, t8[i * 4 + 3]);
            }
        }
    }
#pragma unroll
    for (int i = 0; i < 8; ++i) {
        int c = (cq << 3) + i;
        float inv = g2[c] * rsqrtf(v2[c] + 1e-5f);
        float sh  = b2[c] - m2[c] * inv;
        T2[w32 * 66 + c] = fmaxf(fmaf(t8[i], inv, sh), 0.f);
    }
    __syncthreads();

    float rT[64];
#pragma unroll
    for (int c4 = 0; c4 < 16; ++c4)
        *(float4*)&rT[c4 << 2] = *(const float4*)&T2[w32 * 66 + (c4 << 2)];

    const int hw = (h << 6) + wbase + w32;
#pragma unroll 2
    for (int oo = 0; oo < 8; ++oo) {
        int o = (cq << 3) + oo;
        float inv = g3[o] * rsqrtf(v3[o] + 1e-5f);
        float sh  = b3[o] - m3[o] * inv;
        float acc = 0.f;
#pragma unroll
        for (int c = 0; c < 64; ++c) acc = fmaf(w3[o * 64 + c], rT[c], acc);
        size_t idx = (((size_t)((b << 6) + o)) << 12) + hw;
        out[idx] = fmaf(acc, inv, sh) + x[idx];
    }
}

// ---------------------------------------------------------------------------
extern "C" void kernel_launch(void* const* d_in, const int* in_sizes, int n_in,
                              void* d_out, int out_size, void* d_ws, size_t ws_size,
                              hipStream_t stream)
{
    const float* x  = (const float*)d_in[0];
    const float* w1 = (const float*)d_in[1];
    const float* g1 = (const float*)d_in[2];
    const float* b1 = (const float*)d_in[3];
    const float* m1 = (const float*)d_in[4];
    const float* v1 = (const float*)d_in[5];
    const float* w2 = (const float*)d_in[6];
    const float* g2 = (const float*)d_in[7];
    const float* b2 = (const float*)d_in[8];
    const float* m2 = (const float*)d_in[9];
    const float* v2 = (const float*)d_in[10];
    const float* w3 = (const float*)d_in[11];
    const float* g3 = (const float*)d_in[12];
    const float* b3 = (const float*)d_in[13];
    const float* m3 = (const float*)d_in[14];
    const float* v3 = (const float*)d_in[15];
    float* out = (float*)d_out;

    // ws: xT 4MB | vbf 4MB | O 4MB (bf16, normalized)
    unsigned short* xT  = (unsigned short*)d_ws;
    unsigned short* vbf = xT + (size_t)8 * 4096 * 64;
    unsigned short* Obase = (unsigned short*)((char*)d_ws + (8u << 20));

    k_prep<<<1024, 256, 0, stream>>>(x, w1, g1, b1, m1, v1, xT, vbf);
    k_attn<<<256, 1024, 0, stream>>>(xT, vbf, Obase);
    k_post<<<1024, 256, 0, stream>>>(Obase, x, w2, g2, b2, m2, v2,
                                     w3, g3, b3, m3, v3, out);
}

// Round 11
// 180.210 us; speedup vs baseline: 1.1658x; 1.0170x over previous
//
#include <hip/hip_runtime.h>
#include <stdint.h>

typedef __attribute__((ext_vector_type(8)))  short s16x8;   // 8 x bf16
typedef __attribute__((ext_vector_type(16))) float f32x16;  // 32x32 MFMA acc
typedef __attribute__((ext_vector_type(2)))  unsigned u32x2;

union CvtI4 { int4 i; s16x8 s; };
union CvtU4 { uint4 u; s16x8 s; };

__device__ __forceinline__ unsigned f2bf(float f) {
    union { float f; unsigned u; } v; v.f = f;
    return (v.u + 0x7fffu + ((v.u >> 16) & 1u)) >> 16;     // RNE
}

// pack two f32 -> (bf16(lo) | bf16(hi)<<16), round-half-up (v12-verified idiom)
__device__ __forceinline__ unsigned packbf(float lo, float hi) {
    union { float f; unsigned u; } a0, a1;
    a0.f = lo; a1.f = hi;
    return __builtin_amdgcn_perm(a1.u + 0x8000u, a0.u + 0x8000u, 0x07060302u);
}

// ---------------------------------------------------------------------------
// k_prep v3: emits MFMA fragment-order layouts (for v21's barrier-free attn).
//   xTf:  [b][st=n>>5][kk=0..3][lane=0..63] 16B blocks; lane l = (n&31)+32*hb
//         holds bf16(x*QS) for row n, c = 16*kk + 8*hb + e  (A/B frag order).
//   vbff: [b][tile=n>>6][s][ksl][dl][lane] 16B blocks; lane l = (d&31)+32*hb
//         holds relu(bn1(w1.x)) for d-row, m = tile*64+(s*4+ksl*2+hb)*8+e.
// Values identical to the old xT/vbf; only addresses changed (verified maps).
// grid 1024 = (b, n0g, half), 256 thr.
// ---------------------------------------------------------------------------
__global__ __launch_bounds__(256) void k_prep(
    const float* __restrict__ x, const float* __restrict__ w1,
    const float* __restrict__ g1, const float* __restrict__ b1,
    const float* __restrict__ m1, const float* __restrict__ v1,
    unsigned short* __restrict__ xTf, unsigned short* __restrict__ vbff)
{
    __shared__ float X[64 * 65];   // [c][n] pad+1
    const int b    = blockIdx.x >> 7;
    const int n0g  = (blockIdx.x >> 1) & 63;
    const int n0   = n0g << 6;
    const int half = blockIdx.x & 1;
    const int tid  = threadIdx.x;
    const float QS = 0.42466090014400953f;   // sqrt(log2(e)/8)

    {
        const int r = tid >> 6, nn = tid & 63;
        const float* xb = x + (size_t)b * 262144 + n0 + nn;
#pragma unroll
        for (int cc = 0; cc < 16; ++cc) {
            int c = cc * 4 + r;
            X[c * 65 + nn] = xb[(size_t)c * 4096];
        }
    }
    __syncthreads();

    {   // xTf fragment write: thread (n8, c8) -> block (st, kk=c8>>1), lane n8+32*(c8&1)
        const int n8 = tid >> 3, c8 = tid & 7;
        const int kk = c8 >> 1, hb = c8 & 1;
        const int st = (n0g << 1) + half;         // global 32-row strip
        const int N  = (half << 5) + n8;          // local row in X
        unsigned u[4];
#pragma unroll
        for (int j = 0; j < 4; ++j) {
            unsigned lo = f2bf(X[(c8 * 8 + 2 * j) * 65 + N] * QS);
            unsigned hi = f2bf(X[(c8 * 8 + 2 * j + 1) * 65 + N] * QS);
            u[j] = lo | (hi << 16);
        }
        uint4 pk; pk.x = u[0]; pk.y = u[1]; pk.z = u[2]; pk.w = u[3];
        *(uint4*)(xTf + ((((size_t)((b << 7) + st) << 2) + kk) << 9)
                      + ((n8 + (hb << 5)) << 3)) = pk;
    }

    {   // vbff fragment write: V = relu(bn1(conv1x1)), d-half = half
        const int n = tid & 63, og = tid >> 6;
        float rX[64];
#pragma unroll
        for (int c = 0; c < 64; ++c) rX[c] = X[c * 65 + n];
        const int cn = n >> 3, e = n & 7;
        const int sS = cn >> 2, kslS = (cn >> 1) & 1, hb = cn & 1;
        unsigned short* vb = vbff +
            ((((size_t)((b << 6) + n0g) << 3) + (sS << 2) + (kslS << 1) + half) << 9) + e;
#pragma unroll 2
        for (int oo = 0; oo < 8; ++oo) {
            int o = (half << 5) + og * 8 + oo;
            float inv = g1[o] * rsqrtf(v1[o] + 1e-5f);
            float sh  = b1[o] - m1[o] * inv;
            float acc = 0.f;
#pragma unroll
            for (int c = 0; c < 64; ++c) acc = fmaf(w1[o * 64 + c], rX[c], acc);
            int lane = (og * 8 + oo) + (hb << 5);
            vb[lane << 3] = (unsigned short)f2bf(fmaxf(fmaf(acc, inv, sh), 0.f));
        }
    }
}

// ---------------------------------------------------------------------------
// k_attn v21: BARRIER-FREE streaming attention (fragment-order layouts).
// R10 lesson: all barrier-phase schedules (v15-v20) plateau 53-57us with
// pipes SUMMING to wall (lockstep homogeneity). v21 removes LDS+barriers
// from the main loop entirely: each wave streams its Ak/Bv MFMA fragments
// directly from L2 via perfectly-coalesced 1KB loads (fragment-order
// layout from k_prep v3). Waves free-run -> natural de-lockstep; L1/L2
// absorb the 4x same-s fragment re-reads across t2 waves.
// Geometry = v18: grid 256 = (b=XCD, qg2 of 128 q), 16 waves,
// wave = (qd = s + 2*t2, par); wave processes tiles 2*it+par, it=0..31.
// Per tile: 8 coalesced loads -> QK(4 MFMA) -> exp2/pack -> permlane ->
// PV(4 MFMA). Epilogue (par/s-merge via 64KB LDS scratch): v18 verbatim.
// ---------------------------------------------------------------------------
__global__ __launch_bounds__(1024, 4) void k_attn(
    const unsigned short* __restrict__ xTf, const unsigned short* __restrict__ vbff,
    unsigned short* __restrict__ outO)
{
    __shared__ float scr[16384];      // 64KB epilogue scratch (unused in main loop)
    __shared__ float rsL[16][32];
    __shared__ float dnm[128];

    const int b   = blockIdx.x & 7;           // batch == XCD slice
    const int qg2 = blockIdx.x >> 3;          // 0..31 (128-q group)
    const int tid = threadIdx.x;
    const int w = tid >> 6, lane = tid & 63;
    const int l31 = lane & 31, half = lane >> 5;
    const int qbase = qg2 << 7;
    const int qd = w & 7, par = w >> 3;
    const int s  = qd & 1;     // m-strip (QK) / PV m-chunk group
    const int t2 = qd >> 1;    // n-slab (0..3), 32 q rows each

    // ---- Q fragments: blocks (st_q = qg2*4 + t2, kk) ----
    s16x8 Bq[4];
    {
        const unsigned short* qB = xTf +
            (((size_t)((b << 7) + (qg2 << 2) + t2)) << 11) + (lane << 3);
#pragma unroll
        for (int kk = 0; kk < 4; ++kk) {
            CvtI4 c; c.i = *(const int4*)(qB + (kk << 9));
            Bq[kk] = c.s;
        }
    }

    // ---- streaming bases: block idx = b*512 + T*8 + s*4 + j, T-stride 4096 ----
    const unsigned short* akB = xTf  + (((size_t)((b << 9) + (s << 2))) << 9) + (lane << 3);
    const unsigned short* bvB = vbff + (((size_t)((b << 9) + (s << 2))) << 9) + (lane << 3);

    f32x16 O[2];
#pragma unroll
    for (int dl = 0; dl < 2; ++dl)
#pragma unroll
        for (int r = 0; r < 16; ++r) O[dl][r] = 0.f;
    float rs = 0.f;

    // ================= main loop: 32 tiles, NO barriers =================
    for (int it = 0; it < 32; ++it) {
        const size_t toff = ((size_t)((it << 1) + par)) << 12;   // T*4096 ushorts

        int4 ar[4], br[4];
#pragma unroll
        for (int kk = 0; kk < 4; ++kk) ar[kk] = *(const int4*)(akB + (kk << 9) + toff);
#pragma unroll
        for (int j = 0; j < 4; ++j)    br[j]  = *(const int4*)(bvB + (j << 9) + toff);

        // ---- QK quadrant (s,t2) of tile T ----
        f32x16 S = {0.f,0.f,0.f,0.f,0.f,0.f,0.f,0.f,0.f,0.f,0.f,0.f,0.f,0.f,0.f,0.f};
        __builtin_amdgcn_s_setprio(1);
        {
            CvtI4 c0; c0.i = ar[0]; S = __builtin_amdgcn_mfma_f32_32x32x16_bf16(c0.s, Bq[0], S, 0, 0, 0);
            CvtI4 c1; c1.i = ar[1]; S = __builtin_amdgcn_mfma_f32_32x32x16_bf16(c1.s, Bq[1], S, 0, 0, 0);
            CvtI4 c2; c2.i = ar[2]; S = __builtin_amdgcn_mfma_f32_32x32x16_bf16(c2.s, Bq[2], S, 0, 0, 0);
            CvtI4 c3; c3.i = ar[3]; S = __builtin_amdgcn_mfma_f32_32x32x16_bf16(c3.s, Bq[3], S, 0, 0, 0);
        }
        __builtin_amdgcn_s_setprio(0);

        // ---- exp2 + pack to bf16 pairs (m-group q, lane-local in n) ----
        uint2 G[4];
#pragma unroll
        for (int q = 0; q < 4; ++q) {
            float p0 = __builtin_amdgcn_exp2f(S[4*q+0]);
            float p1 = __builtin_amdgcn_exp2f(S[4*q+1]);
            float p2 = __builtin_amdgcn_exp2f(S[4*q+2]);
            float p3 = __builtin_amdgcn_exp2f(S[4*q+3]);
            rs += (p0 + p1) + (p2 + p3);
            G[q].x = packbf(p0, p1);
            G[q].y = packbf(p2, p3);
        }

        // ---- PV: in-register P via permlane32_swap; B = streamed V frags ----
        __builtin_amdgcn_s_setprio(1);
#pragma unroll
        for (int ksl = 0; ksl < 2; ++ksl) {
            // swap(a,b) -> r.x = a.lo||b.lo (dw-low), r.y = a.hi||b.hi (dw-high)
            u32x2 r0 = __builtin_amdgcn_permlane32_swap(G[2*ksl].x, G[2*ksl+1].x, false, false);
            u32x2 r1 = __builtin_amdgcn_permlane32_swap(G[2*ksl].y, G[2*ksl+1].y, false, false);
            CvtU4 ac;
            ac.u.x = r0.x; ac.u.y = r1.x; ac.u.z = r0.y; ac.u.w = r1.y;
            const s16x8 Ap = ac.s;
            CvtI4 v0; v0.i = br[2*ksl + 0];
            CvtI4 v1; v1.i = br[2*ksl + 1];
            O[0] = __builtin_amdgcn_mfma_f32_32x32x16_bf16(Ap, v0.s, O[0], 0, 0, 0);
            O[1] = __builtin_amdgcn_mfma_f32_32x32x16_bf16(Ap, v1.s, O[1], 0, 0, 0);
        }
        __builtin_amdgcn_s_setprio(0);
    }

    // ================= epilogue: par-merge -> s-merge -> store =============
    float* scrK = scr;            // 8192 f32
    float* scrV = scr + 8192;     // 8192 f32

    rs += __shfl_xor(rs, 32);
    if (half == 0) rsL[w][l31] = rs;

    if (par == 1) {       // par-merge write: region qd (8 regions x 2048 f32)
        float* rg = (qd < 4) ? (scrK + (qd << 11)) : (scrV + ((qd - 4) << 11));
#pragma unroll
        for (int dl = 0; dl < 2; ++dl)
#pragma unroll
            for (int r = 0; r < 16; ++r)
                rg[(dl << 10) + (r << 6) + lane] = O[dl][r];
    }
    __syncthreads();

    if (tid < 128) {      // denom: 4 contributing waves per n-slab
        int tt = tid >> 5, n32 = tid & 31;
        dnm[tid] = (rsL[(tt << 1) + 0][n32] + rsL[(tt << 1) + 1][n32]) +
                   (rsL[(tt << 1) + 8][n32] + rsL[(tt << 1) + 9][n32]);
    }
    if (par == 0) {       // par-merge read
        float* rg = (qd < 4) ? (scrK + (qd << 11)) : (scrV + ((qd - 4) << 11));
#pragma unroll
        for (int dl = 0; dl < 2; ++dl)
#pragma unroll
            for (int r = 0; r < 16; ++r)
                O[dl][r] += rg[(dl << 10) + (r << 6) + lane];
    }
    __syncthreads();

    if (par == 0 && s == 1) {   // s-merge write: region t2 (4 x 2048 f32 in scrK)
#pragma unroll
        for (int dl = 0; dl < 2; ++dl)
#pragma unroll
            for (int r = 0; r < 16; ++r)
                scrK[(t2 << 11) + (dl << 10) + (r << 6) + lane] = O[dl][r];
    }
    __syncthreads();

    if (par == 0 && s == 0) {
        const int nb = (b << 12) + qbase;
#pragma unroll
        for (int dl = 0; dl < 2; ++dl)
#pragma unroll
            for (int r = 0; r < 16; ++r) {
                int rowoff = (r & 3) + ((r >> 2) << 3) + (half << 2);
                int n = (t2 << 5) + rowoff;
                float o = O[dl][r] + scrK[(t2 << 11) + (dl << 10) + (r << 6) + lane];
                outO[((size_t)(nb + n) << 6) + (dl << 5) + l31] =
                    (unsigned short)f2bf(o * (1.f / dnm[n]));
            }
    }
}

// ---------------------------------------------------------------------------
// k_post v2: w-half split. grid 1024 = (b, h, wh), 256 thr.
// ---------------------------------------------------------------------------
__global__ __launch_bounds__(256) void k_post(
    const unsigned short* __restrict__ Obase,
    const float* __restrict__ x,
    const float* __restrict__ w2,
    const float* __restrict__ g2, const float* __restrict__ b2,
    const float* __restrict__ m2, const float* __restrict__ v2,
    const float* __restrict__ w3,
    const float* __restrict__ g3, const float* __restrict__ b3,
    const float* __restrict__ m3, const float* __restrict__ v3,
    float* __restrict__ out)
{
    __shared__ float W[3][34 * 66];   // [row][col][ch] (+2 pad per col)
    __shared__ float T2[32 * 66];

    const int b  = blockIdx.x >> 7;
    const int h  = (blockIdx.x >> 1) & 63;
    const int wh = blockIdx.x & 1;
    const int wbase = wh << 5;
    const int tid = threadIdx.x;

#pragma unroll
    for (int r = 0; r < 3; ++r) {
        int hh = h + r - 1;
#pragma unroll
        for (int i = 0; i < 2; ++i) {
            int lin = (i << 8) + tid;
            if (lin < 272) {
                int wl = lin >> 3, cg = lin & 7;
                int wg = wbase + wl - 1;
                float* Wd = &W[r][wl * 66 + (cg << 3)];
                if (hh >= 0 && hh <= 63 && wg >= 0 && wg <= 63) {
                    size_t npos = (size_t)((b << 12) + (hh << 6) + wg);
                    uint4 v = *(const uint4*)(Obase + (npos << 6) + (cg << 3));
                    union { float f; unsigned u; } t;
                    t.u = v.x << 16;         Wd[0] = t.f;
                    t.u = v.x & 0xFFFF0000u; Wd[1] = t.f;
                    t.u = v.y << 16;         Wd[2] = t.f;
                    t.u = v.y & 0xFFFF0000u; Wd[3] = t.f;
                    t.u = v.z << 16;         Wd[4] = t.f;
                    t.u = v.z & 0xFFFF0000u; Wd[5] = t.f;
                    t.u = v.w << 16;         Wd[6] = t.f;
                    t.u = v.w & 0xFFFF0000u; Wd[7] = t.f;
                } else {
#pragma unroll
                    for (int j = 0; j < 8; ++j) Wd[j] = 0.f;
                }
            }
        }
    }
    __syncthreads();

    const int w32 = tid & 31, cq = tid >> 5;   // cq in [0,8): 8 channels
    float t8[8];
#pragma unroll
    for (int i = 0; i < 8; ++i) t8[i] = 0.f;

#pragma unroll
    for (int ky = 0; ky < 3; ++ky) {
#pragma unroll
        for (int kx = 0; kx < 3; ++kx) {
            const int k = ky * 3 + kx;
            const float* Wr = &W[ky][(w32 + kx) * 66 + (cq << 3)];
#pragma unroll
            for (int i = 0; i < 2; ++i) {
                float4 a = *(const float4*)(Wr + (i << 2));
                int c = (cq << 3) + (i << 2);
                t8[i * 4 + 0] = fmaf(w2[(c + 0) * 9 + k], a.x, t8[i * 4 + 0]);
                t8[i * 4 + 1] = fmaf(w2[(c + 1) * 9 + k], a.y, t8[i * 4 + 1]);
                t8[i * 4 + 2] = fmaf(w2[(c + 2) * 9 + k], a.z, t8[i * 4 + 2]);
                t8[i * 4 + 3] = fmaf(w2[(c + 3) * 9 + k], a.w, t8[i * 4 + 3]);
            }
        }
    }
#pragma unroll
    for (int i = 0; i < 8; ++i) {
        int c = (cq << 3) + i;
        float inv = g2[c] * rsqrtf(v2[c] + 1e-5f);
        float sh  = b2[c] - m2[c] * inv;
        T2[w32 * 66 + c] = fmaxf(fmaf(t8[i], inv, sh), 0.f);
    }
    __syncthreads();

    float rT[64];
#pragma unroll
    for (int c4 = 0; c4 < 16; ++c4)
        *(float4*)&rT[c4 << 2] = *(const float4*)&T2[w32 * 66 + (c4 << 2)];

    const int hw = (h << 6) + wbase + w32;
#pragma unroll 2
    for (int oo = 0; oo < 8; ++oo) {
        int o = (cq << 3) + oo;
        float inv = g3[o] * rsqrtf(v3[o] + 1e-5f);
        float sh  = b3[o] - m3[o] * inv;
        float acc = 0.f;
#pragma unroll
        for (int c = 0; c < 64; ++c) acc = fmaf(w3[o * 64 + c], rT[c], acc);
        size_t idx = (((size_t)((b << 6) + o)) << 12) + hw;
        out[idx] = fmaf(acc, inv, sh) + x[idx];
    }
}

// ---------------------------------------------------------------------------
extern "C" void kernel_launch(void* const* d_in, const int* in_sizes, int n_in,
                              void* d_out, int out_size, void* d_ws, size_t ws_size,
                              hipStream_t stream)
{
    const float* x  = (const float*)d_in[0];
    const float* w1 = (const float*)d_in[1];
    const float* g1 = (const float*)d_in[2];
    const float* b1 = (const float*)d_in[3];
    const float* m1 = (const float*)d_in[4];
    const float* v1 = (const float*)d_in[5];
    const float* w2 = (const float*)d_in[6];
    const float* g2 = (const float*)d_in[7];
    const float* b2 = (const float*)d_in[8];
    const float* m2 = (const float*)d_in[9];
    const float* v2 = (const float*)d_in[10];
    const float* w3 = (const float*)d_in[11];
    const float* g3 = (const float*)d_in[12];
    const float* b3 = (const float*)d_in[13];
    const float* m3 = (const float*)d_in[14];
    const float* v3 = (const float*)d_in[15];
    float* out = (float*)d_out;

    // ws: xTf 4MB | vbff 4MB | O 4MB (bf16, normalized)
    unsigned short* xTf  = (unsigned short*)d_ws;
    unsigned short* vbff = xTf + (size_t)8 * 4096 * 64;
    unsigned short* Obase = (unsigned short*)((char*)d_ws + (8u << 20));

    k_prep<<<1024, 256, 0, stream>>>(x, w1, g1, b1, m1, v1, xTf, vbff);
    k_attn<<<256, 1024, 0, stream>>>(xTf, vbff, Obase);
    k_post<<<1024, 256, 0, stream>>>(Obase, x, w2, g2, b2, m2, v2,
                                     w3, g3, b3, m3, v3, out);
}